// Round 1
// baseline (281.770 us; speedup 1.0000x reference)
//
#include <hip/hip_runtime.h>
#include <cstdint>

#define N_IMG 1024
#define D_DIM 512
#define C_CLS 100000
#define C_PAD 100096            // 782 * 128
#define SCALE_LN2 92.33248261689366f  // 64 / ln(2)
#define COS_M 0.8775825618903728f
#define SIN_M 0.479425538604203f

typedef __attribute__((ext_vector_type(8))) short short8v;
typedef __attribute__((ext_vector_type(4))) float f32x4;

static __device__ __forceinline__ ushort f2bf(float x) {
  uint32_t u = __builtin_bit_cast(uint32_t, x);
  u += 0x7fffu + ((u >> 16) & 1u);   // round-to-nearest-even
  return (ushort)(u >> 16);
}

#define GLD16(g, l) __builtin_amdgcn_global_load_lds( \
    (const __attribute__((address_space(1))) void*)(g), \
    (__attribute__((address_space(3))) void*)(l), 16, 0, 0)

// ---------------------------------------------------------------- zero init
__global__ void zero_kernel(float* p, int n) {
  int i = blockIdx.x * blockDim.x + threadIdx.x;
  if (i < n) p[i] = 0.f;
}

// ------------------------------------------------- row L2-normalize -> bf16
// one wave per row; D=512 -> 8 f32/lane
__global__ __launch_bounds__(256) void norm_rows(
    const float* __restrict__ src, ushort* __restrict__ dst,
    float* __restrict__ inv, int nvalid, int nrows)
{
  int row = blockIdx.x * 4 + (threadIdx.x >> 6);
  int lane = threadIdx.x & 63;
  if (row >= nrows) return;
  if (row >= nvalid) {                 // pad rows: zero-fill bf16 buffer
    uint2 z; z.x = 0u; z.y = 0u;
    ((uint2*)(dst + (size_t)row * D_DIM))[lane] = z;
    ((uint2*)(dst + (size_t)row * D_DIM + 256))[lane] = z;
    return;
  }
  const float4* sp = (const float4*)(src + (size_t)row * D_DIM);
  float4 a = sp[lane], b = sp[lane + 64];
  float ss = a.x*a.x + a.y*a.y + a.z*a.z + a.w*a.w
           + b.x*b.x + b.y*b.y + b.z*b.z + b.w*b.w;
  #pragma unroll
  for (int off = 1; off < 64; off <<= 1) ss += __shfl_xor(ss, off);
  float iv = 1.0f / fmaxf(sqrtf(ss), 1e-12f);
  if (lane == 0) inv[row] = iv;
  ushort4 o1, o2;
  o1.x = f2bf(a.x * iv); o1.y = f2bf(a.y * iv);
  o1.z = f2bf(a.z * iv); o1.w = f2bf(a.w * iv);
  o2.x = f2bf(b.x * iv); o2.y = f2bf(b.y * iv);
  o2.z = f2bf(b.z * iv); o2.w = f2bf(b.w * iv);
  ((ushort4*)(dst + (size_t)row * D_DIM))[lane] = o1;
  ((ushort4*)(dst + (size_t)row * D_DIM + 256))[lane] = o2;
}

// ------------------------------------------- fused GEMM + exp + row-reduce
// C[n][c] = sum_k A[n][k] * B[c][k]   (both row-major along K: B^T GEMM)
// 128x128 tile, BK=64, 4 waves in 2x2, each wave 64x64 (4x4 frags 16x16x32).
// LDS stored with T2 XOR-swizzle via pre-swizzled global source (G4/m173).
__global__ __launch_bounds__(256) void gemm_fused(
    const ushort* __restrict__ A, const ushort* __restrict__ B,
    float* __restrict__ row_sums)
{
  __shared__ __align__(16) ushort As[128 * 64];
  __shared__ __align__(16) ushort Bs[128 * 64];
  const int tid  = threadIdx.x;
  const int lane = tid & 63;
  const int wid  = tid >> 6;
  const int bm = blockIdx.x & 7;          // 8 M-tiles (1024/128)
  const int bn = blockIdx.x >> 3;         // 782 N-tiles
  const int wr = wid >> 1, wc = wid & 1;  // 2x2 wave grid

  f32x4 acc[4][4] = {};

  // staging: lane l writes LDS bytes [base + l*16); source col pre-swizzled
  const int srow = lane >> 3;                       // row within 8-row group
  const int scol = ((lane & 7) ^ srow) << 3;        // element col (swizzled)
  const size_t a_base = (size_t)(bm * 128) * D_DIM;
  const size_t b_base = (size_t)(bn * 128) * D_DIM;

  for (int kt = 0; kt < 8; ++kt) {
    if (kt) __syncthreads();
    const int kofs = kt * 64;
    #pragma unroll
    for (int i = 0; i < 4; ++i) {
      const int r0 = wid * 32 + i * 8;
      GLD16(A + a_base + (size_t)(r0 + srow) * D_DIM + kofs + scol, &As[r0 * 64]);
    }
    #pragma unroll
    for (int i = 0; i < 4; ++i) {
      const int r0 = wid * 32 + i * 8;
      GLD16(B + b_base + (size_t)(r0 + srow) * D_DIM + kofs + scol, &Bs[r0 * 64]);
    }
    asm volatile("s_waitcnt vmcnt(0)" ::: "memory");
    __syncthreads();

    #pragma unroll
    for (int kk = 0; kk < 2; ++kk) {
      const int ke = kk * 32 + (lane >> 4) * 8;     // k element for this lane
      short8v af[4], bf[4];
      #pragma unroll
      for (int m = 0; m < 4; ++m) {
        int row = wr * 64 + m * 16 + (lane & 15);
        int byt = (row << 7) + (ke << 1);
        byt ^= (row & 7) << 4;
        af[m] = *(const short8v*)((const char*)As + byt);
      }
      #pragma unroll
      for (int n = 0; n < 4; ++n) {
        int row = wc * 64 + n * 16 + (lane & 15);
        int byt = (row << 7) + (ke << 1);
        byt ^= (row & 7) << 4;
        bf[n] = *(const short8v*)((const char*)Bs + byt);
      }
      #pragma unroll
      for (int m = 0; m < 4; ++m)
        #pragma unroll
        for (int n = 0; n < 4; ++n)
          acc[m][n] = __builtin_amdgcn_mfma_f32_16x16x32_bf16(
              af[m], bf[n], acc[m][n], 0, 0, 0);
    }
  }

  // epilogue: clip, exp(64x), reduce over this block's 128 cols per row
  // C/D layout (m89): col = lane&15, row = (lane>>4)*4 + reg
  const int rbase = bm * 128 + wr * 64 + (lane >> 4) * 4;
  const int cbase = bn * 128 + wc * 64 + (lane & 15);
  #pragma unroll
  for (int m = 0; m < 4; ++m) {
    #pragma unroll
    for (int j = 0; j < 4; ++j) {
      float s = 0.f;
      #pragma unroll
      for (int n = 0; n < 4; ++n) {
        int gcol = cbase + n * 16;
        float v = acc[m][n][j];
        v = fminf(fmaxf(v, -1.f), 1.f);
        float e = __builtin_amdgcn_exp2f(v * SCALE_LN2);
        s += (gcol < C_CLS) ? e : 0.f;
      }
      #pragma unroll
      for (int off = 1; off < 16; off <<= 1) s += __shfl_xor(s, off);
      if ((lane & 15) == 0)
        atomicAdd(&row_sums[rbase + m * 16 + j], s);
    }
  }
}

// ---------------------------------------- per-row margin fixup + row loss
__global__ __launch_bounds__(256) void fix_loss(
    const float* __restrict__ images, const float* __restrict__ weight,
    const int* __restrict__ labels, const float* __restrict__ img_inv,
    const float* __restrict__ w_inv, const float* __restrict__ row_sums,
    float* __restrict__ loss_buf)
{
  int row = blockIdx.x * 4 + (threadIdx.x >> 6);
  int lane = threadIdx.x & 63;
  int lab = labels[row];
  const float4* ip = (const float4*)(images + (size_t)row * D_DIM);
  const float4* wp = (const float4*)(weight + (size_t)lab * D_DIM);
  float4 a = ip[lane],      b = wp[lane];
  float4 a2 = ip[lane + 64], b2 = wp[lane + 64];
  float dot = a.x*b.x + a.y*b.y + a.z*b.z + a.w*b.w
            + a2.x*b2.x + a2.y*b2.y + a2.z*b2.z + a2.w*b2.w;
  #pragma unroll
  for (int off = 1; off < 64; off <<= 1) dot += __shfl_xor(dot, off);
  if (lane == 0) {
    float t = dot * img_inv[row] * w_inv[lab];
    t = fminf(fmaxf(t, -1.f), 1.f);
    float tadj = t * COS_M - sqrtf(fmaxf(1.f - t * t, 0.f)) * SIN_M;
    float s = row_sums[row]
            - __builtin_amdgcn_exp2f(t    * SCALE_LN2)
            + __builtin_amdgcn_exp2f(tadj * SCALE_LN2);
    loss_buf[row] = logf(s) - 64.f * tadj;
  }
}

// ------------------------------------------------------------ final mean
__global__ void final_reduce(const float* __restrict__ loss_buf,
                             float* __restrict__ out)
{
  __shared__ float sh[16];
  int tid = threadIdx.x;
  float v = loss_buf[tid];
  #pragma unroll
  for (int off = 1; off < 64; off <<= 1) v += __shfl_xor(v, off);
  if ((tid & 63) == 0) sh[tid >> 6] = v;
  __syncthreads();
  if (tid < 16) {
    float w = sh[tid];
    #pragma unroll
    for (int off = 1; off < 16; off <<= 1) w += __shfl_xor(w, off);
    if (tid == 0) out[0] = w * (1.0f / 1024.0f);
  }
}

// ----------------------------------------------------------------- launch
extern "C" void kernel_launch(void* const* d_in, const int* in_sizes, int n_in,
                              void* d_out, int out_size, void* d_ws, size_t ws_size,
                              hipStream_t stream) {
  const float* images = (const float*)d_in[0];
  const int*   labels = (const int*)d_in[1];
  const float* weight = (const float*)d_in[2];
  float* out = (float*)d_out;
  char* ws = (char*)d_ws;

  // workspace layout (all 16B-aligned)
  float*  row_sums = (float*)(ws + 0);          //  4 KB
  float*  loss_buf = (float*)(ws + 4096);       //  4 KB
  float*  img_inv  = (float*)(ws + 8192);       //  4 KB
  float*  w_inv    = (float*)(ws + 12288);      //  400 KB
  ushort* ne       = (ushort*)(ws + 412672);    //  1 MB   [1024][512] bf16
  ushort* nw       = (ushort*)(ws + 1461248);   //  ~98 MB [100096][512] bf16

  zero_kernel<<<4, 256, 0, stream>>>(row_sums, N_IMG);
  norm_rows<<<N_IMG / 4, 256, 0, stream>>>(images, ne, img_inv, N_IMG, N_IMG);
  norm_rows<<<C_PAD / 4, 256, 0, stream>>>(weight, nw, w_inv, C_CLS, C_PAD);
  gemm_fused<<<8 * (C_PAD / 128), 256, 0, stream>>>(ne, nw, row_sums);
  fix_loss<<<N_IMG / 4, 256, 0, stream>>>(images, weight, labels, img_inv,
                                          w_inv, row_sums, loss_buf);
  final_reduce<<<1, 1024, 0, stream>>>(loss_buf, out);
}

// Round 2
// 266.811 us; speedup vs baseline: 1.0561x; 1.0561x over previous
//
#include <hip/hip_runtime.h>
#include <cstdint>

#define N_IMG 1024
#define D_DIM 512
#define C_CLS 100000
#define C_PAD 100096            // 782 * 128
#define NTILE_N 782
#define SCALE_LN2 92.33248261689366f  // 64 / ln(2)
#define COS_M 0.8775825618903728f
#define SIN_M 0.479425538604203f

typedef __attribute__((ext_vector_type(8))) short short8v;
typedef __attribute__((ext_vector_type(4))) float f32x4;

static __device__ __forceinline__ ushort f2bf(float x) {
  uint32_t u = __builtin_bit_cast(uint32_t, x);
  u += 0x7fffu + ((u >> 16) & 1u);   // round-to-nearest-even
  return (ushort)(u >> 16);
}

#define GLD16(g, l) __builtin_amdgcn_global_load_lds( \
    (const __attribute__((address_space(1))) void*)(g), \
    (__attribute__((address_space(3))) void*)(l), 16, 0, 0)

// ---------------------------------------------------------------- zero init
__global__ void zero_kernel(float* p, int n) {
  int i = blockIdx.x * blockDim.x + threadIdx.x;
  if (i < n) p[i] = 0.f;
}

// ------------------------------------------------- row L2-normalize -> bf16
__global__ __launch_bounds__(256) void norm_rows(
    const float* __restrict__ src, ushort* __restrict__ dst,
    float* __restrict__ inv, int nvalid, int nrows)
{
  int row = blockIdx.x * 4 + (threadIdx.x >> 6);
  int lane = threadIdx.x & 63;
  if (row >= nrows) return;
  if (row >= nvalid) {                 // pad rows: zero-fill bf16 buffer
    uint2 z; z.x = 0u; z.y = 0u;
    ((uint2*)(dst + (size_t)row * D_DIM))[lane] = z;
    ((uint2*)(dst + (size_t)row * D_DIM + 256))[lane] = z;
    return;
  }
  const float4* sp = (const float4*)(src + (size_t)row * D_DIM);
  float4 a = sp[lane], b = sp[lane + 64];
  float ss = a.x*a.x + a.y*a.y + a.z*a.z + a.w*a.w
           + b.x*b.x + b.y*b.y + b.z*b.z + b.w*b.w;
  #pragma unroll
  for (int off = 1; off < 64; off <<= 1) ss += __shfl_xor(ss, off);
  float iv = 1.0f / fmaxf(sqrtf(ss), 1e-12f);
  if (lane == 0) inv[row] = iv;
  ushort4 o1, o2;
  o1.x = f2bf(a.x * iv); o1.y = f2bf(a.y * iv);
  o1.z = f2bf(a.z * iv); o1.w = f2bf(a.w * iv);
  o2.x = f2bf(b.x * iv); o2.y = f2bf(b.y * iv);
  o2.z = f2bf(b.z * iv); o2.w = f2bf(b.w * iv);
  ((ushort4*)(dst + (size_t)row * D_DIM))[lane] = o1;
  ((ushort4*)(dst + (size_t)row * D_DIM + 256))[lane] = o2;
}

// ------------------------------------------- fused GEMM + exp + row-reduce
// C[n][c] = sum_k A[n][k] * B[c][k]  (B^T GEMM), 128x128 tile, BK=64,
// double-buffered LDS (T3-minimum 2-phase), XCD-chunked block swizzle (T1),
// T2 XOR-swizzle via pre-swizzled global source.
__global__ __launch_bounds__(256) void gemm_fused(
    const ushort* __restrict__ A, const ushort* __restrict__ B,
    float* __restrict__ row_sums)
{
  __shared__ __align__(16) ushort As[2][128 * 64];
  __shared__ __align__(16) ushort Bs[2][128 * 64];
  const int tid  = threadIdx.x;
  const int lane = tid & 63;
  const int wid  = tid >> 6;

  // T1: nwg = 6256 = 8 * 782. xcd = p%8 gets contiguous chunk of 782 slots;
  // within a chunk, g%8 = bm (8 M-tiles of one bn adjacent -> same L2).
  const int p = blockIdx.x;
  const int g = (p & 7) * NTILE_N + (p >> 3);
  const int bm = g & 7;
  const int bn = g >> 3;
  const int wr = wid >> 1, wc = wid & 1;  // 2x2 wave grid

  f32x4 acc[4][4] = {};

  // staging geometry: lane l writes LDS bytes [wave_base + l*16)
  const int srow = lane >> 3;                       // row within 8-row group
  const int scol = ((lane & 7) ^ srow) << 3;        // element col (swizzled)
  const size_t a_base = (size_t)(bm * 128) * D_DIM;
  const size_t b_base = (size_t)(bn * 128) * D_DIM;

  #define STAGE(buf, kt) do {                                                 \
    const int kofs_ = (kt) * 64;                                              \
    _Pragma("unroll")                                                         \
    for (int i_ = 0; i_ < 4; ++i_) {                                          \
      const int r0_ = wid * 32 + i_ * 8;                                      \
      GLD16(A + a_base + (size_t)(r0_ + srow) * D_DIM + kofs_ + scol,         \
            &As[buf][r0_ * 64]);                                              \
      GLD16(B + b_base + (size_t)(r0_ + srow) * D_DIM + kofs_ + scol,         \
            &Bs[buf][r0_ * 64]);                                              \
    }                                                                         \
  } while (0)

  // prologue
  STAGE(0, 0);
  asm volatile("s_waitcnt vmcnt(0)" ::: "memory");
  __syncthreads();

  int cur = 0;
  for (int kt = 0; kt < 8; ++kt) {
    if (kt < 7) STAGE(cur ^ 1, kt + 1);   // issue next tile's loads first

    const char* Ab = (const char*)As[cur];
    const char* Bb = (const char*)Bs[cur];
    #pragma unroll
    for (int kk = 0; kk < 2; ++kk) {
      const int ke = kk * 32 + (lane >> 4) * 8;     // k element for this lane
      short8v af[4], bf[4];
      #pragma unroll
      for (int m = 0; m < 4; ++m) {
        int row = wr * 64 + m * 16 + (lane & 15);
        int byt = (row << 7) + (ke << 1);
        byt ^= (row & 7) << 4;
        af[m] = *(const short8v*)(Ab + byt);
      }
      #pragma unroll
      for (int n = 0; n < 4; ++n) {
        int row = wc * 64 + n * 16 + (lane & 15);
        int byt = (row << 7) + (ke << 1);
        byt ^= (row & 7) << 4;
        bf[n] = *(const short8v*)(Bb + byt);
      }
      #pragma unroll
      for (int m = 0; m < 4; ++m)
        #pragma unroll
        for (int n = 0; n < 4; ++n)
          acc[m][n] = __builtin_amdgcn_mfma_f32_16x16x32_bf16(
              af[m], bf[n], acc[m][n], 0, 0, 0);
    }

    asm volatile("s_waitcnt vmcnt(0)" ::: "memory");  // next-tile stage done
    __syncthreads();
    cur ^= 1;
  }
  #undef STAGE

  // epilogue: clip, exp(64x), reduce over this block's 128 cols per row
  // C/D layout (m89): col = lane&15, row = (lane>>4)*4 + reg
  const int rbase = bm * 128 + wr * 64 + (lane >> 4) * 4;
  const int cbase = bn * 128 + wc * 64 + (lane & 15);
  #pragma unroll
  for (int m = 0; m < 4; ++m) {
    #pragma unroll
    for (int j = 0; j < 4; ++j) {
      float s = 0.f;
      #pragma unroll
      for (int n = 0; n < 4; ++n) {
        int gcol = cbase + n * 16;
        float v = acc[m][n][j];
        v = fminf(fmaxf(v, -1.f), 1.f);
        float e = __builtin_amdgcn_exp2f(v * SCALE_LN2);
        s += (gcol < C_CLS) ? e : 0.f;
      }
      #pragma unroll
      for (int off = 1; off < 16; off <<= 1) s += __shfl_xor(s, off);
      if ((lane & 15) == 0)
        atomicAdd(&row_sums[rbase + m * 16 + j], s);
    }
  }
}

// ---------------------------------------- per-row margin fixup + row loss
__global__ __launch_bounds__(256) void fix_loss(
    const float* __restrict__ images, const float* __restrict__ weight,
    const int* __restrict__ labels, const float* __restrict__ img_inv,
    const float* __restrict__ w_inv, const float* __restrict__ row_sums,
    float* __restrict__ loss_buf)
{
  int row = blockIdx.x * 4 + (threadIdx.x >> 6);
  int lane = threadIdx.x & 63;
  int lab = labels[row];
  const float4* ip = (const float4*)(images + (size_t)row * D_DIM);
  const float4* wp = (const float4*)(weight + (size_t)lab * D_DIM);
  float4 a = ip[lane],      b = wp[lane];
  float4 a2 = ip[lane + 64], b2 = wp[lane + 64];
  float dot = a.x*b.x + a.y*b.y + a.z*b.z + a.w*b.w
            + a2.x*b2.x + a2.y*b2.y + a2.z*b2.z + a2.w*b2.w;
  #pragma unroll
  for (int off = 1; off < 64; off <<= 1) dot += __shfl_xor(dot, off);
  if (lane == 0) {
    float t = dot * img_inv[row] * w_inv[lab];
    t = fminf(fmaxf(t, -1.f), 1.f);
    float tadj = t * COS_M - sqrtf(fmaxf(1.f - t * t, 0.f)) * SIN_M;
    float s = row_sums[row]
            - __builtin_amdgcn_exp2f(t    * SCALE_LN2)
            + __builtin_amdgcn_exp2f(tadj * SCALE_LN2);
    loss_buf[row] = logf(s) - 64.f * tadj;
  }
}

// ------------------------------------------------------------ final mean
__global__ void final_reduce(const float* __restrict__ loss_buf,
                             float* __restrict__ out)
{
  __shared__ float sh[16];
  int tid = threadIdx.x;
  float v = loss_buf[tid];
  #pragma unroll
  for (int off = 1; off < 64; off <<= 1) v += __shfl_xor(v, off);
  if ((tid & 63) == 0) sh[tid >> 6] = v;
  __syncthreads();
  if (tid < 16) {
    float w = sh[tid];
    #pragma unroll
    for (int off = 1; off < 16; off <<= 1) w += __shfl_xor(w, off);
    if (tid == 0) out[0] = w * (1.0f / 1024.0f);
  }
}

// ----------------------------------------------------------------- launch
extern "C" void kernel_launch(void* const* d_in, const int* in_sizes, int n_in,
                              void* d_out, int out_size, void* d_ws, size_t ws_size,
                              hipStream_t stream) {
  const float* images = (const float*)d_in[0];
  const int*   labels = (const int*)d_in[1];
  const float* weight = (const float*)d_in[2];
  float* out = (float*)d_out;
  char* ws = (char*)d_ws;

  // workspace layout (all 16B-aligned)
  float*  row_sums = (float*)(ws + 0);          //  4 KB
  float*  loss_buf = (float*)(ws + 4096);       //  4 KB
  float*  img_inv  = (float*)(ws + 8192);       //  4 KB
  float*  w_inv    = (float*)(ws + 12288);      //  400 KB
  ushort* ne       = (ushort*)(ws + 412672);    //  1 MB   [1024][512] bf16
  ushort* nw       = (ushort*)(ws + 1461248);   //  ~98 MB [100096][512] bf16

  zero_kernel<<<4, 256, 0, stream>>>(row_sums, N_IMG);
  norm_rows<<<N_IMG / 4, 256, 0, stream>>>(images, ne, img_inv, N_IMG, N_IMG);
  norm_rows<<<C_PAD / 4, 256, 0, stream>>>(weight, nw, w_inv, C_CLS, C_PAD);
  gemm_fused<<<8 * NTILE_N, 256, 0, stream>>>(ne, nw, row_sums);
  fix_loss<<<N_IMG / 4, 256, 0, stream>>>(images, weight, labels, img_inv,
                                          w_inv, row_sums, loss_buf);
  final_reduce<<<1, 1024, 0, stream>>>(loss_buf, out);
}

// Round 3
// 219.070 us; speedup vs baseline: 1.2862x; 1.2179x over previous
//
#include <hip/hip_runtime.h>
#include <cstdint>

#define N_IMG 1024
#define D_DIM 512
#define C_CLS 100000
#define C_PAD 100096            // 391 * 256
#define NT_N 391
#define NWG (4 * NT_N)          // 1564 blocks
#define SCALE_LN2 92.33248261689366f  // 64 / ln(2)
#define COS_M 0.8775825618903728f
#define SIN_M 0.479425538604203f

typedef __attribute__((ext_vector_type(8))) short short8v;
typedef __attribute__((ext_vector_type(4))) float f32x4;

static __device__ __forceinline__ ushort f2bf(float x) {
  uint32_t u = __builtin_bit_cast(uint32_t, x);
  u += 0x7fffu + ((u >> 16) & 1u);   // round-to-nearest-even
  return (ushort)(u >> 16);
}

#define GLD16(g, l) __builtin_amdgcn_global_load_lds( \
    (const __attribute__((address_space(1))) void*)(g), \
    (__attribute__((address_space(3))) void*)(l), 16, 0, 0)

// ------------------------------------------------- row L2-normalize -> bf16
__global__ __launch_bounds__(256) void norm_rows(
    const float* __restrict__ src, ushort* __restrict__ dst,
    float* __restrict__ inv, int nvalid, int nrows)
{
  int row = blockIdx.x * 4 + (threadIdx.x >> 6);
  int lane = threadIdx.x & 63;
  if (row >= nrows) return;
  if (row >= nvalid) {                 // pad rows: zero-fill bf16 buffer
    uint2 z; z.x = 0u; z.y = 0u;
    ((uint2*)(dst + (size_t)row * D_DIM))[lane] = z;
    ((uint2*)(dst + (size_t)row * D_DIM + 256))[lane] = z;
    return;
  }
  const float4* sp = (const float4*)(src + (size_t)row * D_DIM);
  float4 a = sp[lane], b = sp[lane + 64];
  float ss = a.x*a.x + a.y*a.y + a.z*a.z + a.w*a.w
           + b.x*b.x + b.y*b.y + b.z*b.z + b.w*b.w;
  #pragma unroll
  for (int off = 1; off < 64; off <<= 1) ss += __shfl_xor(ss, off);
  float iv = 1.0f / fmaxf(sqrtf(ss), 1e-12f);
  if (lane == 0) inv[row] = iv;
  ushort4 o1, o2;
  o1.x = f2bf(a.x * iv); o1.y = f2bf(a.y * iv);
  o1.z = f2bf(a.z * iv); o1.w = f2bf(a.w * iv);
  o2.x = f2bf(b.x * iv); o2.y = f2bf(b.y * iv);
  o2.z = f2bf(b.z * iv); o2.w = f2bf(b.w * iv);
  ((ushort4*)(dst + (size_t)row * D_DIM))[lane] = o1;
  ((ushort4*)(dst + (size_t)row * D_DIM + 256))[lane] = o2;
}

// ------------------------------------------- fused GEMM + exp + row-reduce
// 256x256 tile, BK=64, 8 waves (2Mx4N), 4-phase/K-tile counted-vmcnt schedule
// (T3+T4), setprio around MFMA (T5), T1 bijective XCD swizzle, 3-bit XOR LDS
// swizzle (verified 0 bank conflicts in rounds 1-2).
//
// Staging rounds per K-tile (1 GLD16/wave each, 8 waves cover 64 rows/round):
//   r0..r3 : B rows [r*64, r*64+64)
//   r4: A[0..64) r5: A[128..192) r6: A[64..128) r7: A[192..256)
// Phase p of iter kt issues rounds 2p,2p+1 of tile kt+1.
// Read deps: phase0 reads B(all)=r0-3, A rows wr*128+[0,64) = r4(wr0)/r5(wr1)
//   -> gated by vmcnt(2)+barrier at END of previous iter (r0-r5 oldest done).
// phase1 reads A rows wr*128+[64,128) = r6(wr0)/r7(wr1)
//   -> gated by vmcnt(2)+barrier at end of phase0 (outstanding = r6,r7 of cur
//      tile + 2 just-issued -> all-but-2-newest = r6,r7 done).
// phases 2,3 re-read same LDS rows at kk=1: no new deps.
__global__ __launch_bounds__(512, 2) void gemm_fused(
    const ushort* __restrict__ A, const ushort* __restrict__ B,
    float* __restrict__ partials)
{
  __shared__ __align__(16) ushort As[2][256 * 64];
  __shared__ __align__(16) ushort Bs[2][256 * 64];
  __shared__ float red[256];

  const int tid  = threadIdx.x;
  const int lane = tid & 63;
  const int w    = tid >> 6;
  const int l15  = lane & 15;
  const int l4   = lane >> 4;

  // T1 bijective swizzle: NWG=1564, q=195, r=4
  const int p   = blockIdx.x;
  const int xcd = p & 7, idx = p >> 3;
  const int g   = (xcd < 4 ? xcd * 196 : 784 + (xcd - 4) * 195) + idx;
  const int bm  = g & 3;
  const int bn  = g >> 2;
  const int wr  = w >> 2, wc = w & 3;   // 2x4 wave grid

  f32x4 acc[8][4] = {};
  if (tid < 256) red[tid] = 0.f;

  // staging geometry: lane l -> local row l>>3, slot l&7, swizzled source col
  const int srow = lane >> 3;
  const int scol = ((lane & 7) ^ srow) << 3;
  const size_t a_base = (size_t)(bm * 256) * D_DIM;
  const size_t b_base = (size_t)(bn * 256) * D_DIM;

  #define STG_B(buf, kt, rblk) GLD16( \
      B + b_base + (size_t)((rblk)*64 + w*8 + srow) * D_DIM + (kt)*64 + scol, \
      &Bs[buf][((rblk)*64 + w*8) * 64])
  #define STG_A(buf, kt, rowoff) GLD16( \
      A + a_base + (size_t)((rowoff) + w*8 + srow) * D_DIM + (kt)*64 + scol, \
      &As[buf][((rowoff) + w*8) * 64])

  #define READ_A(mg, kk) do { _Pragma("unroll") \
    for (int mi = 0; mi < 4; ++mi) { \
      int row = wr*128 + (mg)*64 + mi*16 + l15; \
      int byt = (row << 7) + (((kk)*32 + l4*8) << 1); \
      byt ^= (row & 7) << 4; \
      afr[mi] = *(const short8v*)(Ab + byt); } } while (0)
  #define READ_B(kk) do { _Pragma("unroll") \
    for (int n = 0; n < 4; ++n) { \
      int row = wc*64 + n*16 + l15; \
      int byt = (row << 7) + (((kk)*32 + l4*8) << 1); \
      byt ^= (row & 7) << 4; \
      bfr[n] = *(const short8v*)(Bb + byt); } } while (0)
  #define MFMA16(mg) do { _Pragma("unroll") \
    for (int mi = 0; mi < 4; ++mi) { _Pragma("unroll") \
      for (int n = 0; n < 4; ++n) \
        acc[(mg)*4+mi][n] = __builtin_amdgcn_mfma_f32_16x16x32_bf16( \
            afr[mi], bfr[n], acc[(mg)*4+mi][n], 0, 0, 0); } } while (0)

  #define BAR()    __builtin_amdgcn_s_barrier()
  #define FENCE()  asm volatile("" ::: "memory")
  #define LGKM0()  do { asm volatile("s_waitcnt lgkmcnt(0)" ::: "memory"); \
                        __builtin_amdgcn_sched_barrier(0); } while (0)
  #define VM(n)    asm volatile("s_waitcnt vmcnt(" #n ")" ::: "memory")

  // prologue: stage tile 0 fully, drain once
  STG_B(0, 0, 0); STG_B(0, 0, 1); STG_B(0, 0, 2); STG_B(0, 0, 3);
  STG_A(0, 0, 0); STG_A(0, 0, 128); STG_A(0, 0, 64); STG_A(0, 0, 192);
  VM(0);
  BAR();

  #pragma unroll 1
  for (int kt = 0; kt < 8; ++kt) {
    const int cur = kt & 1, nxt = cur ^ 1;
    const char* Ab = (const char*)As[cur];
    const char* Bb = (const char*)Bs[cur];
    const bool hn = (kt < 7);
    short8v afr[4], bfr[4];

    // ---- phase 0: (kk=0, mg=0)
    READ_B(0); READ_A(0, 0);
    if (hn) { STG_B(nxt, kt + 1, 0); STG_B(nxt, kt + 1, 1); }
    FENCE(); BAR(); LGKM0();
    __builtin_amdgcn_s_setprio(1);
    MFMA16(0);
    __builtin_amdgcn_s_setprio(0);
    if (hn) { VM(2); } else { VM(0); }   // gate r6,r7 of current tile
    BAR(); FENCE();

    // ---- phase 1: (kk=0, mg=1)
    READ_A(1, 0);
    if (hn) { STG_B(nxt, kt + 1, 2); STG_B(nxt, kt + 1, 3); }
    FENCE(); BAR(); LGKM0();
    __builtin_amdgcn_s_setprio(1);
    MFMA16(1);
    __builtin_amdgcn_s_setprio(0);
    BAR(); FENCE();

    // ---- phase 2: (kk=1, mg=0)
    READ_B(1); READ_A(0, 1);
    if (hn) { STG_A(nxt, kt + 1, 0); STG_A(nxt, kt + 1, 128); }
    FENCE(); BAR(); LGKM0();
    __builtin_amdgcn_s_setprio(1);
    MFMA16(0);
    __builtin_amdgcn_s_setprio(0);
    BAR(); FENCE();

    // ---- phase 3: (kk=1, mg=1)
    READ_A(1, 1);
    if (hn) { STG_A(nxt, kt + 1, 64); STG_A(nxt, kt + 1, 192); }
    FENCE(); BAR(); LGKM0();
    __builtin_amdgcn_s_setprio(1);
    MFMA16(1);
    __builtin_amdgcn_s_setprio(0);
    if (hn) { VM(2); }                   // gate r0-r5 of next tile
    BAR(); FENCE();
  }

  // epilogue: clip, exp(64x), reduce 256 block-cols per row into red[],
  // then one non-atomic partials store per (bn,row).
  // C/D layout (m89): col = lane&15, row_in_frag = (lane>>4)*4 + j
  #pragma unroll
  for (int m = 0; m < 8; ++m) {
    #pragma unroll
    for (int j = 0; j < 4; ++j) {
      float s = 0.f;
      #pragma unroll
      for (int n = 0; n < 4; ++n) {
        int gcol = bn * 256 + wc * 64 + n * 16 + l15;
        float v = acc[m][n][j];
        v = fminf(fmaxf(v, -1.f), 1.f);
        float e = __builtin_amdgcn_exp2f(v * SCALE_LN2);
        s += (gcol < C_CLS) ? e : 0.f;
      }
      #pragma unroll
      for (int off = 1; off < 16; off <<= 1) s += __shfl_xor(s, off);
      if (l15 == 0)
        atomicAdd(&red[wr * 128 + m * 16 + l4 * 4 + j], s);  // LDS, 4-way max
    }
  }
  __syncthreads();
  if (tid < 256)
    partials[(size_t)bn * 1024 + bm * 256 + tid] = red[tid];

  #undef STG_B
  #undef STG_A
  #undef READ_A
  #undef READ_B
  #undef MFMA16
  #undef BAR
  #undef FENCE
  #undef LGKM0
  #undef VM
}

// -------------------------------------------- row_sums[r] = sum_bn partials
__global__ __launch_bounds__(256) void reduce_partials(
    const float* __restrict__ partials, float* __restrict__ row_sums)
{
  int gid = blockIdx.x * 256 + threadIdx.x;   // 0..1023
  float s = 0.f;
  for (int bn = 0; bn < NT_N; ++bn)
    s += partials[(size_t)bn * 1024 + gid];
  row_sums[gid] = s;
}

// ---------------------------------------- per-row margin fixup + row loss
__global__ __launch_bounds__(256) void fix_loss(
    const float* __restrict__ images, const float* __restrict__ weight,
    const int* __restrict__ labels, const float* __restrict__ img_inv,
    const float* __restrict__ w_inv, const float* __restrict__ row_sums,
    float* __restrict__ loss_buf)
{
  int row = blockIdx.x * 4 + (threadIdx.x >> 6);
  int lane = threadIdx.x & 63;
  int lab = labels[row];
  const float4* ip = (const float4*)(images + (size_t)row * D_DIM);
  const float4* wp = (const float4*)(weight + (size_t)lab * D_DIM);
  float4 a = ip[lane],      b = wp[lane];
  float4 a2 = ip[lane + 64], b2 = wp[lane + 64];
  float dot = a.x*b.x + a.y*b.y + a.z*b.z + a.w*b.w
            + a2.x*b2.x + a2.y*b2.y + a2.z*b2.z + a2.w*b2.w;
  #pragma unroll
  for (int off = 1; off < 64; off <<= 1) dot += __shfl_xor(dot, off);
  if (lane == 0) {
    float t = dot * img_inv[row] * w_inv[lab];
    t = fminf(fmaxf(t, -1.f), 1.f);
    float tadj = t * COS_M - sqrtf(fmaxf(1.f - t * t, 0.f)) * SIN_M;
    float s = row_sums[row]
            - __builtin_amdgcn_exp2f(t    * SCALE_LN2)
            + __builtin_amdgcn_exp2f(tadj * SCALE_LN2);
    loss_buf[row] = logf(s) - 64.f * tadj;
  }
}

// ------------------------------------------------------------ final mean
__global__ void final_reduce(const float* __restrict__ loss_buf,
                             float* __restrict__ out)
{
  __shared__ float sh[16];
  int tid = threadIdx.x;
  float v = loss_buf[tid];
  #pragma unroll
  for (int off = 1; off < 64; off <<= 1) v += __shfl_xor(v, off);
  if ((tid & 63) == 0) sh[tid >> 6] = v;
  __syncthreads();
  if (tid < 16) {
    float w = sh[tid];
    #pragma unroll
    for (int off = 1; off < 16; off <<= 1) w += __shfl_xor(w, off);
    if (tid == 0) out[0] = w * (1.0f / 1024.0f);
  }
}

// ----------------------------------------------------------------- launch
extern "C" void kernel_launch(void* const* d_in, const int* in_sizes, int n_in,
                              void* d_out, int out_size, void* d_ws, size_t ws_size,
                              hipStream_t stream) {
  const float* images = (const float*)d_in[0];
  const int*   labels = (const int*)d_in[1];
  const float* weight = (const float*)d_in[2];
  float* out = (float*)d_out;
  char* ws = (char*)d_ws;

  // workspace layout (all 16B-aligned)
  float*  row_sums = (float*)(ws + 0);          //  4 KB
  float*  loss_buf = (float*)(ws + 4096);       //  4 KB
  float*  img_inv  = (float*)(ws + 8192);       //  4 KB
  float*  w_inv    = (float*)(ws + 12288);      //  400 KB
  ushort* ne       = (ushort*)(ws + 412672);    //  1 MB    [1024][512] bf16
  float*  partials = (float*)(ws + 1461248);    //  ~1.6 MB [391][1024] f32
  ushort* nw       = (ushort*)(ws + 3064832);   //  ~98 MB  [100096][512] bf16

  norm_rows<<<N_IMG / 4, 256, 0, stream>>>(images, ne, img_inv, N_IMG, N_IMG);
  norm_rows<<<C_PAD / 4, 256, 0, stream>>>(weight, nw, w_inv, C_CLS, C_PAD);
  gemm_fused<<<NWG, 512, 0, stream>>>(ne, nw, partials);
  reduce_partials<<<4, 256, 0, stream>>>(partials, row_sums);
  fix_loss<<<N_IMG / 4, 256, 0, stream>>>(images, weight, labels, img_inv,
                                          w_inv, row_sums, loss_buf);
  final_reduce<<<1, 1024, 0, stream>>>(loss_buf, out);
}

// Round 4
// 210.692 us; speedup vs baseline: 1.3374x; 1.0398x over previous
//
#include <hip/hip_runtime.h>
#include <cstdint>

#define N_IMG 1024
#define D_DIM 512
#define C_CLS 100000
#define C_PAD 100096            // 391 * 256
#define NT_N 391
#define NWG (4 * NT_N)          // 1564 blocks
#define SCALE_LN2 92.33248261689366f  // 64 / ln(2)
#define COS_M 0.8775825618903728f
#define SIN_M 0.479425538604203f

typedef __attribute__((ext_vector_type(8))) short short8v;
typedef __attribute__((ext_vector_type(4))) float f32x4;

static __device__ __forceinline__ ushort f2bf(float x) {
  uint32_t u = __builtin_bit_cast(uint32_t, x);
  u += 0x7fffu + ((u >> 16) & 1u);   // round-to-nearest-even
  return (ushort)(u >> 16);
}

#define GLD16(g, l) __builtin_amdgcn_global_load_lds( \
    (const __attribute__((address_space(1))) void*)(g), \
    (__attribute__((address_space(3))) void*)(l), 16, 0, 0)

// ------------------------------------------------- row L2-normalize -> bf16
__global__ __launch_bounds__(256) void norm_rows(
    const float* __restrict__ src, ushort* __restrict__ dst,
    float* __restrict__ inv, int nvalid, int nrows)
{
  int row = blockIdx.x * 4 + (threadIdx.x >> 6);
  int lane = threadIdx.x & 63;
  if (row >= nrows) return;
  if (row >= nvalid) {                 // pad rows: zero-fill bf16 buffer
    uint2 z; z.x = 0u; z.y = 0u;
    ((uint2*)(dst + (size_t)row * D_DIM))[lane] = z;
    ((uint2*)(dst + (size_t)row * D_DIM + 256))[lane] = z;
    return;
  }
  const float4* sp = (const float4*)(src + (size_t)row * D_DIM);
  float4 a = sp[lane], b = sp[lane + 64];
  float ss = a.x*a.x + a.y*a.y + a.z*a.z + a.w*a.w
           + b.x*b.x + b.y*b.y + b.z*b.z + b.w*b.w;
  #pragma unroll
  for (int off = 1; off < 64; off <<= 1) ss += __shfl_xor(ss, off);
  float iv = 1.0f / fmaxf(sqrtf(ss), 1e-12f);
  if (lane == 0) inv[row] = iv;
  ushort4 o1, o2;
  o1.x = f2bf(a.x * iv); o1.y = f2bf(a.y * iv);
  o1.z = f2bf(a.z * iv); o1.w = f2bf(a.w * iv);
  o2.x = f2bf(b.x * iv); o2.y = f2bf(b.y * iv);
  o2.z = f2bf(b.z * iv); o2.w = f2bf(b.w * iv);
  ((ushort4*)(dst + (size_t)row * D_DIM))[lane] = o1;
  ((ushort4*)(dst + (size_t)row * D_DIM + 256))[lane] = o2;
}

// ------------------------------------------- fused GEMM + exp + row-reduce
// 256x256 tile, BK=64, 8 waves (2Mx4N). One barrier + one own-wave vmcnt(0)
// per K-tile; K-loop FULLY UNROLLED so the compiler software-pipelines
// ds_read<->MFMA with its own fine-grained lgkmcnt (no asm drains inside the
// region). Stage loads for tile kt+1 issue at region start -> vmcnt(0) at
// region end waits only on ~2.5k-cycle-old loads (~0 stall).
// T1 bijective XCD swizzle, 3-bit XOR LDS swizzle (0 conflicts, verified).
__global__ __launch_bounds__(512, 2) void gemm_fused(
    const ushort* __restrict__ A, const ushort* __restrict__ B,
    float* __restrict__ partials)
{
  __shared__ __align__(16) ushort As[2][256 * 64];
  __shared__ __align__(16) ushort Bs[2][256 * 64];
  __shared__ float red[256];

  const int tid  = threadIdx.x;
  const int lane = tid & 63;
  const int w    = tid >> 6;
  const int l15  = lane & 15;
  const int l4   = lane >> 4;

  // T1 bijective swizzle: NWG=1564, q=195, r=4
  const int p   = blockIdx.x;
  const int xcd = p & 7, idx = p >> 3;
  const int g   = (xcd < 4 ? xcd * 196 : 784 + (xcd - 4) * 195) + idx;
  const int bm  = g & 3;
  const int bn  = g >> 2;
  const int wr  = w >> 2, wc = w & 3;   // 2x4 wave grid

  f32x4 acc[8][4] = {};
  if (tid < 256) red[tid] = 0.f;

  // staging geometry: lane l -> local row l>>3, slot l&7, swizzled source col
  const int srow = lane >> 3;
  const int scol = ((lane & 7) ^ srow) << 3;
  const size_t a_base = (size_t)(bm * 256) * D_DIM;
  const size_t b_base = (size_t)(bn * 256) * D_DIM;

  #define STG_B(buf, kt, rblk) GLD16( \
      B + b_base + (size_t)((rblk)*64 + w*8 + srow) * D_DIM + (kt)*64 + scol, \
      &Bs[buf][((rblk)*64 + w*8) * 64])
  #define STG_A(buf, kt, rblk) GLD16( \
      A + a_base + (size_t)((rblk)*64 + w*8 + srow) * D_DIM + (kt)*64 + scol, \
      &As[buf][((rblk)*64 + w*8) * 64])
  #define STAGE_ALL(buf, kt) do { \
    STG_B(buf, kt, 0); STG_B(buf, kt, 1); STG_B(buf, kt, 2); STG_B(buf, kt, 3); \
    STG_A(buf, kt, 0); STG_A(buf, kt, 1); STG_A(buf, kt, 2); STG_A(buf, kt, 3); \
  } while (0)

  #define READ_A(dst, mg, kk) do { _Pragma("unroll") \
    for (int mi = 0; mi < 4; ++mi) { \
      int row = wr*128 + (mg)*64 + mi*16 + l15; \
      int byt = (row << 7) + (((kk)*32 + l4*8) << 1); \
      byt ^= (row & 7) << 4; \
      dst[mi] = *(const short8v*)(Ab + byt); } } while (0)
  #define READ_B(dst, kk) do { _Pragma("unroll") \
    for (int n = 0; n < 4; ++n) { \
      int row = wc*64 + n*16 + l15; \
      int byt = (row << 7) + (((kk)*32 + l4*8) << 1); \
      byt ^= (row & 7) << 4; \
      dst[n] = *(const short8v*)(Bb + byt); } } while (0)
  #define MFMA16(mg, af) do { _Pragma("unroll") \
    for (int mi = 0; mi < 4; ++mi) { _Pragma("unroll") \
      for (int n = 0; n < 4; ++n) \
        acc[(mg)*4+mi][n] = __builtin_amdgcn_mfma_f32_16x16x32_bf16( \
            af[mi], bfr[n], acc[(mg)*4+mi][n], 0, 0, 0); } } while (0)

  #define BAR()   do { asm volatile("" ::: "memory"); \
                       __builtin_amdgcn_s_barrier(); \
                       asm volatile("" ::: "memory"); } while (0)
  #define VM0()   asm volatile("s_waitcnt vmcnt(0)" ::: "memory")

  // prologue: stage tile 0, drain, barrier
  STAGE_ALL(0, 0);
  VM0();
  BAR();

  #pragma unroll
  for (int kt = 0; kt < 8; ++kt) {
    const int cur = kt & 1;
    const char* Ab = (const char*)As[cur];
    const char* Bb = (const char*)Bs[cur];

    if (kt < 7) STAGE_ALL(cur ^ 1, kt + 1);   // issue early, wait late

    short8v af0[4], af1[4], bfr[4];
    // kk = 0
    READ_B(bfr, 0); READ_A(af0, 0, 0); READ_A(af1, 1, 0);
    MFMA16(0, af0);
    MFMA16(1, af1);
    // kk = 1
    READ_B(bfr, 1); READ_A(af0, 0, 1); READ_A(af1, 1, 1);
    MFMA16(0, af0);
    MFMA16(1, af1);

    if (kt < 7) VM0();    // own stage loads: issued a full K-tile ago
    BAR();
  }

  // epilogue: clip, exp(64x), reduce 256 block-cols per row into red[],
  // then one non-atomic partials store per (bn,row).
  // C/D layout (m89): col = lane&15, row_in_frag = (lane>>4)*4 + j
  #pragma unroll
  for (int m = 0; m < 8; ++m) {
    #pragma unroll
    for (int j = 0; j < 4; ++j) {
      float s = 0.f;
      #pragma unroll
      for (int n = 0; n < 4; ++n) {
        int gcol = bn * 256 + wc * 64 + n * 16 + l15;
        float v = acc[m][n][j];
        v = fminf(fmaxf(v, -1.f), 1.f);
        float e = __builtin_amdgcn_exp2f(v * SCALE_LN2);
        s += (gcol < C_CLS) ? e : 0.f;
      }
      #pragma unroll
      for (int off = 1; off < 16; off <<= 1) s += __shfl_xor(s, off);
      if (l15 == 0)
        atomicAdd(&red[wr * 128 + m * 16 + l4 * 4 + j], s);  // LDS, 4-way max
    }
  }
  __syncthreads();
  if (tid < 256)
    partials[(size_t)bn * 1024 + bm * 256 + tid] = red[tid];

  #undef STG_B
  #undef STG_A
  #undef STAGE_ALL
  #undef READ_A
  #undef READ_B
  #undef MFMA16
  #undef BAR
  #undef VM0
}

// -------------------------------------------- row_sums[r] = sum_bn partials
__global__ __launch_bounds__(256) void reduce_partials(
    const float* __restrict__ partials, float* __restrict__ row_sums)
{
  int gid = blockIdx.x * 256 + threadIdx.x;   // 0..1023
  float s = 0.f;
  for (int bn = 0; bn < NT_N; ++bn)
    s += partials[(size_t)bn * 1024 + gid];
  row_sums[gid] = s;
}

// ---------------------------------------- per-row margin fixup + row loss
__global__ __launch_bounds__(256) void fix_loss(
    const float* __restrict__ images, const float* __restrict__ weight,
    const int* __restrict__ labels, const float* __restrict__ img_inv,
    const float* __restrict__ w_inv, const float* __restrict__ row_sums,
    float* __restrict__ loss_buf)
{
  int row = blockIdx.x * 4 + (threadIdx.x >> 6);
  int lane = threadIdx.x & 63;
  int lab = labels[row];
  const float4* ip = (const float4*)(images + (size_t)row * D_DIM);
  const float4* wp = (const float4*)(weight + (size_t)lab * D_DIM);
  float4 a = ip[lane],      b = wp[lane];
  float4 a2 = ip[lane + 64], b2 = wp[lane + 64];
  float dot = a.x*b.x + a.y*b.y + a.z*b.z + a.w*b.w
            + a2.x*b2.x + a2.y*b2.y + a2.z*b2.z + a2.w*b2.w;
  #pragma unroll
  for (int off = 1; off < 64; off <<= 1) dot += __shfl_xor(dot, off);
  if (lane == 0) {
    float t = dot * img_inv[row] * w_inv[lab];
    t = fminf(fmaxf(t, -1.f), 1.f);
    float tadj = t * COS_M - sqrtf(fmaxf(1.f - t * t, 0.f)) * SIN_M;
    float s = row_sums[row]
            - __builtin_amdgcn_exp2f(t    * SCALE_LN2)
            + __builtin_amdgcn_exp2f(tadj * SCALE_LN2);
    loss_buf[row] = logf(s) - 64.f * tadj;
  }
}

// ------------------------------------------------------------ final mean
__global__ void final_reduce(const float* __restrict__ loss_buf,
                             float* __restrict__ out)
{
  __shared__ float sh[16];
  int tid = threadIdx.x;
  float v = loss_buf[tid];
  #pragma unroll
  for (int off = 1; off < 64; off <<= 1) v += __shfl_xor(v, off);
  if ((tid & 63) == 0) sh[tid >> 6] = v;
  __syncthreads();
  if (tid < 16) {
    float w = sh[tid];
    #pragma unroll
    for (int off = 1; off < 16; off <<= 1) w += __shfl_xor(w, off);
    if (tid == 0) out[0] = w * (1.0f / 1024.0f);
  }
}

// ----------------------------------------------------------------- launch
extern "C" void kernel_launch(void* const* d_in, const int* in_sizes, int n_in,
                              void* d_out, int out_size, void* d_ws, size_t ws_size,
                              hipStream_t stream) {
  const float* images = (const float*)d_in[0];
  const int*   labels = (const int*)d_in[1];
  const float* weight = (const float*)d_in[2];
  float* out = (float*)d_out;
  char* ws = (char*)d_ws;

  // workspace layout (all 16B-aligned)
  float*  row_sums = (float*)(ws + 0);          //  4 KB
  float*  loss_buf = (float*)(ws + 4096);       //  4 KB
  float*  img_inv  = (float*)(ws + 8192);       //  4 KB
  float*  w_inv    = (float*)(ws + 12288);      //  400 KB
  ushort* ne       = (ushort*)(ws + 412672);    //  1 MB    [1024][512] bf16
  float*  partials = (float*)(ws + 1461248);    //  ~1.6 MB [391][1024] f32
  ushort* nw       = (ushort*)(ws + 3064832);   //  ~98 MB  [100096][512] bf16

  norm_rows<<<N_IMG / 4, 256, 0, stream>>>(images, ne, img_inv, N_IMG, N_IMG);
  norm_rows<<<C_PAD / 4, 256, 0, stream>>>(weight, nw, w_inv, C_CLS, C_PAD);
  gemm_fused<<<NWG, 512, 0, stream>>>(ne, nw, partials);
  reduce_partials<<<4, 256, 0, stream>>>(partials, row_sums);
  fix_loss<<<N_IMG / 4, 256, 0, stream>>>(images, weight, labels, img_inv,
                                          w_inv, row_sums, loss_buf);
  final_reduce<<<1, 1024, 0, stream>>>(loss_buf, out);
}

// Round 5
// 182.947 us; speedup vs baseline: 1.5402x; 1.1517x over previous
//
#include <hip/hip_runtime.h>
#include <cstdint>

#define N_IMG 1024
#define D_DIM 512
#define C_CLS 100000
#define C_PAD 100096            // 391 * 256
#define NT_N 391
#define NWG (4 * NT_N)          // 1564 blocks
#define SCALE_LN2 92.33248261689366f  // 64 / ln(2)
#define COS_M 0.8775825618903728f
#define SIN_M 0.479425538604203f

typedef __attribute__((ext_vector_type(4))) int int4v;

#define GLD16(g, l) __builtin_amdgcn_global_load_lds( \
    (const __attribute__((address_space(1))) void*)(g), \
    (__attribute__((address_space(3))) void*)(l), 16, 0, 0)

static __device__ __forceinline__ uint pk4(float a, float b, float c, float d,
                                           float qs) {
  int ia = (int)rintf(a * qs), ib = (int)rintf(b * qs);
  int ic = (int)rintf(c * qs), id = (int)rintf(d * qs);
  return (ia & 255) | ((ib & 255) << 8) | ((ic & 255) << 16) | ((id & 255) << 24);
}

static __device__ __forceinline__ int dp8(uint a, uint b) {
  int s = 0;
  #pragma unroll
  for (int i = 0; i < 4; ++i)
    s += (int)(signed char)((a >> (8 * i)) & 255) *
         (int)(signed char)((b >> (8 * i)) & 255);
  return s;
}

// --------------------------- row L2-normalize + symmetric int8 quantization
// q_i = rint(x_i * 127 / amax); dequant scale s_row = amax * inv_norm / 127
// so q_i * s_row ~= x_i / ||x||. One wave per row.
__global__ __launch_bounds__(256) void norm_q(
    const float* __restrict__ src, signed char* __restrict__ dst,
    float* __restrict__ scale, float* __restrict__ inv, int nvalid, int nrows)
{
  int row = blockIdx.x * 4 + (threadIdx.x >> 6);
  int lane = threadIdx.x & 63;
  if (row >= nrows) return;
  if (row >= nvalid) {                 // pad rows: zero q + zero scale
    uint2 z; z.x = 0u; z.y = 0u;
    ((uint2*)(dst + (size_t)row * D_DIM))[lane] = z;
    if (lane == 0) scale[row] = 0.f;
    return;
  }
  const float4* sp = (const float4*)(src + (size_t)row * D_DIM);
  float4 a = sp[2 * lane], b = sp[2 * lane + 1];   // 8 consecutive elements
  float ss = a.x*a.x + a.y*a.y + a.z*a.z + a.w*a.w
           + b.x*b.x + b.y*b.y + b.z*b.z + b.w*b.w;
  float am = fmaxf(fmaxf(fmaxf(fabsf(a.x), fabsf(a.y)),
                         fmaxf(fabsf(a.z), fabsf(a.w))),
                   fmaxf(fmaxf(fabsf(b.x), fabsf(b.y)),
                         fmaxf(fabsf(b.z), fabsf(b.w))));
  #pragma unroll
  for (int off = 1; off < 64; off <<= 1) {
    ss += __shfl_xor(ss, off);
    am = fmaxf(am, __shfl_xor(am, off));
  }
  am = fmaxf(am, 1e-30f);
  float iv = 1.0f / fmaxf(sqrtf(ss), 1e-12f);
  float qs = 127.0f / am;
  if (lane == 0) { inv[row] = iv; scale[row] = am * iv * (1.0f / 127.0f); }
  uint2 o;
  o.x = pk4(a.x, a.y, a.z, a.w, qs);
  o.y = pk4(b.x, b.y, b.z, b.w, qs);
  ((uint2*)(dst + (size_t)row * D_DIM))[lane] = o;
}

// ------------------------------------- fused i8 GEMM + exp + row-reduce
// C[n][c] = (sum_k qA[n][k]*qB[c][k]) * sa[n] * sb[c]   (B^T GEMM)
// 256x256 tile, BK=64, 8 waves (2Mx4N), mfma_i32_16x16x64_i8.
// 3 LDS slots, 2-K-tile-deep prefetch, one counted vmcnt(4) gate per K-tile
// (never 0 in steady state), 2 phases/K-tile {reads | stage 2xGLD | bar |
// setprio 16xMFMA | bar}, fully unrolled. T1 bijective XCD swizzle.
// LDS XOR swizzle: slot' = slot ^ (row&3) on 16B chunks (2-way max = free).
__global__ __launch_bounds__(512, 2) void gemm_fused(
    const signed char* __restrict__ A, const signed char* __restrict__ B,
    const float* __restrict__ sa_img, const float* __restrict__ sb_w,
    float* __restrict__ partials)
{
  __shared__ __align__(16) signed char Aq[3][256 * 64];
  __shared__ __align__(16) signed char Bq[3][256 * 64];
  __shared__ float red[256];

  const int tid  = threadIdx.x;
  const int lane = tid & 63;
  const int w    = tid >> 6;
  const int l15  = lane & 15;
  const int l4   = lane >> 4;

  // T1 bijective swizzle: NWG=1564, q=195, r=4
  const int p   = blockIdx.x;
  const int xcd = p & 7, idx = p >> 3;
  const int g   = (xcd < 4 ? xcd * 196 : 784 + (xcd - 4) * 195) + idx;
  const int bm  = g & 3;
  const int bn  = g >> 2;
  const int wr  = w >> 2, wc = w & 3;   // 2x4 wave grid

  int4v acc[8][4] = {};
  if (tid < 256) red[tid] = 0.f;

  // staging: wave w covers rows [half*128 + w*16, +16); lane -> row w*16+l/4,
  // 16B slot l&3; source slot pre-swizzled by row&3 (= (l>>2)&3)
  const int sgcol = ((lane & 3) ^ ((lane >> 2) & 3)) << 4;
  const int grow  = (w << 4) + (lane >> 2);
  const size_t a_base = (size_t)(bm * 256) * D_DIM;
  const size_t b_base = (size_t)(bn * 256) * D_DIM;
  // read-side swizzle (matches): byte = row*64 + ((l4 ^ (row&3))<<4)
  const int sw4 = ((l4 ^ (l15 & 3)) << 4);

  #define STG_A(slot, kt, half) GLD16( \
      A + a_base + (size_t)((half)*128 + grow) * D_DIM + (kt)*64 + sgcol, \
      &Aq[slot][((half)*128 + (w << 4)) * 64])
  #define STG_B(slot, kt, half) GLD16( \
      B + b_base + (size_t)((half)*128 + grow) * D_DIM + (kt)*64 + sgcol, \
      &Bq[slot][((half)*128 + (w << 4)) * 64])

  #define READ_B() do { _Pragma("unroll") \
    for (int n = 0; n < 4; ++n) { \
      int byt = (wc*64 + n*16 + l15) * 64 + sw4; \
      bf[n] = *(const int4v*)(Bb + byt); } } while (0)
  #define READ_A(mh) do { _Pragma("unroll") \
    for (int mi = 0; mi < 4; ++mi) { \
      int byt = (wr*128 + (mh)*64 + mi*16 + l15) * 64 + sw4; \
      af[mi] = *(const int4v*)(Ab + byt); } } while (0)
  #define MFMA16(mh) do { _Pragma("unroll") \
    for (int mi = 0; mi < 4; ++mi) { _Pragma("unroll") \
      for (int n = 0; n < 4; ++n) \
        acc[(mh)*4+mi][n] = __builtin_amdgcn_mfma_i32_16x16x64_i8( \
            af[mi], bf[n], acc[(mh)*4+mi][n], 0, 0, 0); } } while (0)

  #define BAR()   do { asm volatile("" ::: "memory"); \
                       __builtin_amdgcn_s_barrier(); \
                       asm volatile("" ::: "memory"); } while (0)
  #define VM(n)   asm volatile("s_waitcnt vmcnt(" #n ")" ::: "memory")

  // prologue: stage tiles 0 and 1, wait tile 0 only (tile 1 stays in flight)
  STG_A(0, 0, 0); STG_B(0, 0, 0); STG_A(0, 0, 1); STG_B(0, 0, 1);
  STG_A(1, 1, 0); STG_B(1, 1, 0); STG_A(1, 1, 1); STG_B(1, 1, 1);
  VM(4);
  BAR();

  #pragma unroll
  for (int kt = 0; kt < 8; ++kt) {
    const int sR = kt % 3;            // compile-time (loop unrolled)
    const int sS = (kt + 2) % 3;
    const char* Ab = (const char*)Aq[sR];
    const char* Bb = (const char*)Bq[sR];
    const bool st = (kt < 6);
    int4v af[4], bf[4];

    // ---- phase 0: mh=0
    READ_B(); READ_A(0);
    if (st) { STG_A(sS, kt + 2, 0); STG_B(sS, kt + 2, 0); }
    BAR();
    __builtin_amdgcn_s_setprio(1);
    MFMA16(0);
    __builtin_amdgcn_s_setprio(0);
    BAR();

    // ---- phase 1: mh=1 (bf kept in registers)
    READ_A(1);
    if (st) { STG_A(sS, kt + 2, 1); STG_B(sS, kt + 2, 1); }
    BAR();
    __builtin_amdgcn_s_setprio(1);
    MFMA16(1);
    __builtin_amdgcn_s_setprio(0);
    if (kt < 6)      { VM(4); }   // completes tile kt+1; tile kt+2 in flight
    else if (kt == 6){ VM(0); }   // drain tile 7 (issued during tile 5)
    BAR();
  }

  // epilogue: dequant, clip, exp(64x), reduce 256 block-cols per row
  // C/D layout (m89, dtype-independent): col = lane&15, row = (lane>>4)*4 + j
  const int rowg0 = bm * 256 + wr * 128;
  float sbv[4];
  #pragma unroll
  for (int n = 0; n < 4; ++n)
    sbv[n] = sb_w[bn * 256 + wc * 64 + n * 16 + l15];
  #pragma unroll
  for (int m = 0; m < 8; ++m) {
    #pragma unroll
    for (int j = 0; j < 4; ++j) {
      float sa = sa_img[rowg0 + m * 16 + l4 * 4 + j];
      float s = 0.f;
      #pragma unroll
      for (int n = 0; n < 4; ++n) {
        int gcol = bn * 256 + wc * 64 + n * 16 + l15;
        float ss = sa * sbv[n];
        float v = (float)acc[m][n][j] * ss;
        v = fminf(fmaxf(v, -1.f), 1.f);
        float e = __builtin_amdgcn_exp2f(v * SCALE_LN2);
        s += (gcol < C_CLS) ? e : 0.f;
      }
      #pragma unroll
      for (int off = 1; off < 16; off <<= 1) s += __shfl_xor(s, off);
      if (l15 == 0)
        atomicAdd(&red[wr * 128 + m * 16 + l4 * 4 + j], s);  // LDS, 4-way max
    }
  }
  __syncthreads();
  if (tid < 256)
    partials[(size_t)bn * 1024 + bm * 256 + tid] = red[tid];

  #undef STG_A
  #undef STG_B
  #undef READ_A
  #undef READ_B
  #undef MFMA16
  #undef BAR
  #undef VM
}

// -------------------------------------------- row_sums[r] = sum_bn partials
__global__ __launch_bounds__(256) void reduce_partials(
    const float* __restrict__ partials, float* __restrict__ row_sums)
{
  int gid = blockIdx.x * 256 + threadIdx.x;   // 0..1023
  float s = 0.f;
  for (int bn = 0; bn < NT_N; ++bn)
    s += partials[(size_t)bn * 1024 + gid];
  row_sums[gid] = s;
}

// ---------------------------------------- per-row margin fixup + row loss
// Subtracts the quantized target term BIT-EXACTLY (same i32 dot + same float
// expression as the GEMM epilogue), adds the f32-exact margin term.
__global__ __launch_bounds__(256) void fix_loss(
    const float* __restrict__ images, const float* __restrict__ weight,
    const int* __restrict__ labels, const float* __restrict__ img_inv,
    const float* __restrict__ w_inv,
    const signed char* __restrict__ ne_q, const signed char* __restrict__ nw_q,
    const float* __restrict__ sa_img, const float* __restrict__ sb_w,
    const float* __restrict__ row_sums, float* __restrict__ loss_buf)
{
  int row = blockIdx.x * 4 + (threadIdx.x >> 6);
  int lane = threadIdx.x & 63;
  int lab = labels[row];
  // f32-exact cosine (for the margin term)
  const float4* ip = (const float4*)(images + (size_t)row * D_DIM);
  const float4* wp = (const float4*)(weight + (size_t)lab * D_DIM);
  float4 a = ip[lane],       b = wp[lane];
  float4 a2 = ip[lane + 64], b2 = wp[lane + 64];
  float dot = a.x*b.x + a.y*b.y + a.z*b.z + a.w*b.w
            + a2.x*b2.x + a2.y*b2.y + a2.z*b2.z + a2.w*b2.w;
  // quantized dot (to cancel the GEMM's target term exactly)
  uint2 ua = ((const uint2*)(ne_q + (size_t)row * D_DIM))[lane];
  uint2 ub = ((const uint2*)(nw_q + (size_t)lab * D_DIM))[lane];
  int id = dp8(ua.x, ub.x) + dp8(ua.y, ub.y);
  #pragma unroll
  for (int off = 1; off < 64; off <<= 1) {
    dot += __shfl_xor(dot, off);
    id  += __shfl_xor(id, off);
  }
  if (lane == 0) {
    // quantized target logit — identical expression to GEMM epilogue
    float ss = sa_img[row] * sb_w[lab];
    float vq = (float)id * ss;
    vq = fminf(fmaxf(vq, -1.f), 1.f);
    float eq = __builtin_amdgcn_exp2f(vq * SCALE_LN2);
    // f32-exact target cosine + ArcFace margin
    float t = dot * img_inv[row] * w_inv[lab];
    t = fminf(fmaxf(t, -1.f), 1.f);
    float tadj = t * COS_M - sqrtf(fmaxf(1.f - t * t, 0.f)) * SIN_M;
    float s = row_sums[row] - eq
            + __builtin_amdgcn_exp2f(tadj * SCALE_LN2);
    loss_buf[row] = logf(s) - 64.f * tadj;
  }
}

// ------------------------------------------------------------ final mean
__global__ void final_reduce(const float* __restrict__ loss_buf,
                             float* __restrict__ out)
{
  __shared__ float sh[16];
  int tid = threadIdx.x;
  float v = loss_buf[tid];
  #pragma unroll
  for (int off = 1; off < 64; off <<= 1) v += __shfl_xor(v, off);
  if ((tid & 63) == 0) sh[tid >> 6] = v;
  __syncthreads();
  if (tid < 16) {
    float w = sh[tid];
    #pragma unroll
    for (int off = 1; off < 16; off <<= 1) w += __shfl_xor(w, off);
    if (tid == 0) out[0] = w * (1.0f / 1024.0f);
  }
}

// ----------------------------------------------------------------- launch
extern "C" void kernel_launch(void* const* d_in, const int* in_sizes, int n_in,
                              void* d_out, int out_size, void* d_ws, size_t ws_size,
                              hipStream_t stream) {
  const float* images = (const float*)d_in[0];
  const int*   labels = (const int*)d_in[1];
  const float* weight = (const float*)d_in[2];
  float* out = (float*)d_out;
  char* ws = (char*)d_ws;

  // workspace layout (512B-aligned offsets)
  float*       row_sums = (float*)(ws + 0);          //  4 KB
  float*       loss_buf = (float*)(ws + 4096);       //  4 KB
  float*       img_inv  = (float*)(ws + 8192);       //  4 KB
  float*       w_inv    = (float*)(ws + 12288);      //  ~400 KB
  float*       sa_img   = (float*)(ws + 413696);     //  4 KB
  float*       sb_w     = (float*)(ws + 417792);     //  ~400 KB (C_PAD)
  float*       partials = (float*)(ws + 819200);     //  ~1.6 MB [391][1024]
  signed char* ne_q     = (signed char*)(ws + 2420736);  // 512 KB [1024][512]
  signed char* nw_q     = (signed char*)(ws + 2945024);  // ~51 MB [C_PAD][512]

  norm_q<<<N_IMG / 4, 256, 0, stream>>>(images, ne_q, sa_img, img_inv,
                                        N_IMG, N_IMG);
  norm_q<<<C_PAD / 4, 256, 0, stream>>>(weight, nw_q, sb_w, w_inv,
                                        C_CLS, C_PAD);
  gemm_fused<<<NWG, 512, 0, stream>>>(ne_q, nw_q, sa_img, sb_w, partials);
  reduce_partials<<<4, 256, 0, stream>>>(partials, row_sums);
  fix_loss<<<N_IMG / 4, 256, 0, stream>>>(images, weight, labels, img_inv,
                                          w_inv, ne_q, nw_q, sa_img, sb_w,
                                          row_sums, loss_buf);
  final_reduce<<<1, 1024, 0, stream>>>(loss_buf, out);
}

// Round 6
// 181.642 us; speedup vs baseline: 1.5512x; 1.0072x over previous
//
#include <hip/hip_runtime.h>
#include <cstdint>

#define N_IMG 1024
#define D_DIM 512
#define C_CLS 100000
#define C_PAD 100096            // 391 * 256
#define NT_N 391
#define NWG (4 * NT_N)          // 1564 blocks
#define SCALE_LN2 92.33248261689366f  // 64 / ln(2)
#define COS_M 0.8775825618903728f
#define SIN_M 0.479425538604203f

typedef __attribute__((ext_vector_type(4))) int int4v;

#define GLD16(g, l) __builtin_amdgcn_global_load_lds( \
    (const __attribute__((address_space(1))) void*)(g), \
    (__attribute__((address_space(3))) void*)(l), 16, 0, 0)

static __device__ __forceinline__ uint pk4(float a, float b, float c, float d,
                                           float qs) {
  int ia = (int)rintf(a * qs), ib = (int)rintf(b * qs);
  int ic = (int)rintf(c * qs), id = (int)rintf(d * qs);
  return (ia & 255) | ((ib & 255) << 8) | ((ic & 255) << 16) | ((id & 255) << 24);
}

static __device__ __forceinline__ int dp8(uint a, uint b) {
  int s = 0;
  #pragma unroll
  for (int i = 0; i < 4; ++i)
    s += (int)(signed char)((a >> (8 * i)) & 255) *
         (int)(signed char)((b >> (8 * i)) & 255);
  return s;
}

// --------------------------- row L2-normalize + symmetric int8 quantization
// q_i = rint(x_i * 127 / amax); dequant scale s_row = amax * inv_norm / 127
// so q_i * s_row ~= x_i / ||x||. One wave per row.
__global__ __launch_bounds__(256) void norm_q(
    const float* __restrict__ src, signed char* __restrict__ dst,
    float* __restrict__ scale, float* __restrict__ inv, int nvalid, int nrows)
{
  int row = blockIdx.x * 4 + (threadIdx.x >> 6);
  int lane = threadIdx.x & 63;
  if (row >= nrows) return;
  if (row >= nvalid) {                 // pad rows: zero q + zero scale
    uint2 z; z.x = 0u; z.y = 0u;
    ((uint2*)(dst + (size_t)row * D_DIM))[lane] = z;
    if (lane == 0) scale[row] = 0.f;
    return;
  }
  const float4* sp = (const float4*)(src + (size_t)row * D_DIM);
  float4 a = sp[2 * lane], b = sp[2 * lane + 1];   // 8 consecutive elements
  float ss = a.x*a.x + a.y*a.y + a.z*a.z + a.w*a.w
           + b.x*b.x + b.y*b.y + b.z*b.z + b.w*b.w;
  float am = fmaxf(fmaxf(fmaxf(fabsf(a.x), fabsf(a.y)),
                         fmaxf(fabsf(a.z), fabsf(a.w))),
                   fmaxf(fmaxf(fabsf(b.x), fabsf(b.y)),
                         fmaxf(fabsf(b.z), fabsf(b.w))));
  #pragma unroll
  for (int off = 1; off < 64; off <<= 1) {
    ss += __shfl_xor(ss, off);
    am = fmaxf(am, __shfl_xor(am, off));
  }
  am = fmaxf(am, 1e-30f);
  float iv = 1.0f / fmaxf(sqrtf(ss), 1e-12f);
  float qs = 127.0f / am;
  if (lane == 0) { inv[row] = iv; scale[row] = am * iv * (1.0f / 127.0f); }
  uint2 o;
  o.x = pk4(a.x, a.y, a.z, a.w, qs);
  o.y = pk4(b.x, b.y, b.z, b.w, qs);
  ((uint2*)(dst + (size_t)row * D_DIM))[lane] = o;
}

// ------------------------------------- fused i8 GEMM + exp + row-reduce
// C[n][c] = (sum_k qA[n][k]*qB[c][k]) * sa[n] * sb[c]   (B^T GEMM)
// 256x256 tile, BK=64, 8 waves (2Mx4N), mfma_i32_16x16x64_i8.
// 3 LDS slots, 2-K-tile-deep prefetch, one counted vmcnt(4) gate per K-tile
// (never 0 in steady state), 2 phases/K-tile {reads | stage 2xGLD | bar |
// setprio 16xMFMA | bar}, fully unrolled. T1 bijective XCD swizzle.
// LDS XOR swizzle: slot' = slot ^ (row&3) on 16B chunks (2-way max = free).
__global__ __launch_bounds__(512, 2) void gemm_fused(
    const signed char* __restrict__ A, const signed char* __restrict__ B,
    const float* __restrict__ sa_img, const float* __restrict__ sb_w,
    float* __restrict__ partials)
{
  __shared__ __align__(16) signed char Aq[3][256 * 64];
  __shared__ __align__(16) signed char Bq[3][256 * 64];
  __shared__ float red[256];

  const int tid  = threadIdx.x;
  const int lane = tid & 63;
  const int w    = tid >> 6;
  const int l15  = lane & 15;
  const int l4   = lane >> 4;

  // T1 bijective swizzle: NWG=1564, q=195, r=4
  const int p   = blockIdx.x;
  const int xcd = p & 7, idx = p >> 3;
  const int g   = (xcd < 4 ? xcd * 196 : 784 + (xcd - 4) * 195) + idx;
  const int bm  = g & 3;
  const int bn  = g >> 2;
  const int wr  = w >> 2, wc = w & 3;   // 2x4 wave grid

  int4v acc[8][4] = {};
  if (tid < 256) red[tid] = 0.f;

  // staging: wave w covers rows [half*128 + w*16, +16); lane -> row w*16+l/4,
  // 16B slot l&3; source slot pre-swizzled by row&3 (= (l>>2)&3)
  const int sgcol = ((lane & 3) ^ ((lane >> 2) & 3)) << 4;
  const int grow  = (w << 4) + (lane >> 2);
  const size_t a_base = (size_t)(bm * 256) * D_DIM;
  const size_t b_base = (size_t)(bn * 256) * D_DIM;
  // read-side swizzle (matches): byte = row*64 + ((l4 ^ (row&3))<<4)
  const int sw4 = ((l4 ^ (l15 & 3)) << 4);

  #define STG_A(slot, kt, half) GLD16( \
      A + a_base + (size_t)((half)*128 + grow) * D_DIM + (kt)*64 + sgcol, \
      &Aq[slot][((half)*128 + (w << 4)) * 64])
  #define STG_B(slot, kt, half) GLD16( \
      B + b_base + (size_t)((half)*128 + grow) * D_DIM + (kt)*64 + sgcol, \
      &Bq[slot][((half)*128 + (w << 4)) * 64])

  #define READ_B() do { _Pragma("unroll") \
    for (int n = 0; n < 4; ++n) { \
      int byt = (wc*64 + n*16 + l15) * 64 + sw4; \
      bf[n] = *(const int4v*)(Bb + byt); } } while (0)
  #define READ_A(mh) do { _Pragma("unroll") \
    for (int mi = 0; mi < 4; ++mi) { \
      int byt = (wr*128 + (mh)*64 + mi*16 + l15) * 64 + sw4; \
      af[mi] = *(const int4v*)(Ab + byt); } } while (0)
  #define MFMA16(mh) do { _Pragma("unroll") \
    for (int mi = 0; mi < 4; ++mi) { _Pragma("unroll") \
      for (int n = 0; n < 4; ++n) \
        acc[(mh)*4+mi][n] = __builtin_amdgcn_mfma_i32_16x16x64_i8( \
            af[mi], bf[n], acc[(mh)*4+mi][n], 0, 0, 0); } } while (0)

  #define BAR()   do { asm volatile("" ::: "memory"); \
                       __builtin_amdgcn_s_barrier(); \
                       asm volatile("" ::: "memory"); } while (0)
  #define VM(n)   asm volatile("s_waitcnt vmcnt(" #n ")" ::: "memory")

  // prologue: stage tiles 0 and 1, wait tile 0 only (tile 1 stays in flight)
  STG_A(0, 0, 0); STG_B(0, 0, 0); STG_A(0, 0, 1); STG_B(0, 0, 1);
  STG_A(1, 1, 0); STG_B(1, 1, 0); STG_A(1, 1, 1); STG_B(1, 1, 1);
  VM(4);
  BAR();

  #pragma unroll
  for (int kt = 0; kt < 8; ++kt) {
    const int sR = kt % 3;            // compile-time (loop unrolled)
    const int sS = (kt + 2) % 3;
    const char* Ab = (const char*)Aq[sR];
    const char* Bb = (const char*)Bq[sR];
    const bool st = (kt < 6);
    int4v af[4], bf[4];

    // ---- phase 0: mh=0
    READ_B(); READ_A(0);
    if (st) { STG_A(sS, kt + 2, 0); STG_B(sS, kt + 2, 0); }
    BAR();
    __builtin_amdgcn_s_setprio(1);
    MFMA16(0);
    __builtin_amdgcn_s_setprio(0);
    BAR();

    // ---- phase 1: mh=1 (bf kept in registers)
    READ_A(1);
    if (st) { STG_A(sS, kt + 2, 1); STG_B(sS, kt + 2, 1); }
    BAR();
    __builtin_amdgcn_s_setprio(1);
    MFMA16(1);
    __builtin_amdgcn_s_setprio(0);
    if (kt < 6)      { VM(4); }   // completes tile kt+1; tile kt+2 in flight
    else if (kt == 6){ VM(0); }   // drain tile 7 (issued during tile 5)
    BAR();
  }

  // epilogue: dequant, clip, exp(64x), reduce 256 block-cols per row
  // C/D layout (m89, dtype-independent): col = lane&15, row = (lane>>4)*4 + j
  const int rowg0 = bm * 256 + wr * 128;
  float sbv[4];
  #pragma unroll
  for (int n = 0; n < 4; ++n)
    sbv[n] = sb_w[bn * 256 + wc * 64 + n * 16 + l15];
  #pragma unroll
  for (int m = 0; m < 8; ++m) {
    #pragma unroll
    for (int j = 0; j < 4; ++j) {
      float sa = sa_img[rowg0 + m * 16 + l4 * 4 + j];
      float s = 0.f;
      #pragma unroll
      for (int n = 0; n < 4; ++n) {
        int gcol = bn * 256 + wc * 64 + n * 16 + l15;
        float ss = sa * sbv[n];
        float v = (float)acc[m][n][j] * ss;
        v = fminf(fmaxf(v, -1.f), 1.f);
        float e = __builtin_amdgcn_exp2f(v * SCALE_LN2);
        s += (gcol < C_CLS) ? e : 0.f;
      }
      #pragma unroll
      for (int off = 1; off < 16; off <<= 1) s += __shfl_xor(s, off);
      if (l15 == 0)
        atomicAdd(&red[wr * 128 + m * 16 + l4 * 4 + j], s);  // LDS, 4-way max
    }
  }
  __syncthreads();
  if (tid < 256)
    partials[(size_t)bn * 1024 + bm * 256 + tid] = red[tid];

  #undef STG_A
  #undef STG_B
  #undef READ_A
  #undef READ_B
  #undef MFMA16
  #undef BAR
  #undef VM
}

// -------------------------------------------- row_sums[r] = sum_bn partials
__global__ __launch_bounds__(256) void reduce_partials(
    const float* __restrict__ partials, float* __restrict__ row_sums)
{
  int gid = blockIdx.x * 256 + threadIdx.x;   // 0..1023
  float s = 0.f;
  for (int bn = 0; bn < NT_N; ++bn)
    s += partials[(size_t)bn * 1024 + gid];
  row_sums[gid] = s;
}

// ---------------------------------------- per-row margin fixup + row loss
// Subtracts the quantized target term BIT-EXACTLY (same i32 dot + same float
// expression as the GEMM epilogue), adds the f32-exact margin term.
__global__ __launch_bounds__(256) void fix_loss(
    const float* __restrict__ images, const float* __restrict__ weight,
    const int* __restrict__ labels, const float* __restrict__ img_inv,
    const float* __restrict__ w_inv,
    const signed char* __restrict__ ne_q, const signed char* __restrict__ nw_q,
    const float* __restrict__ sa_img, const float* __restrict__ sb_w,
    const float* __restrict__ row_sums, float* __restrict__ loss_buf)
{
  int row = blockIdx.x * 4 + (threadIdx.x >> 6);
  int lane = threadIdx.x & 63;
  int lab = labels[row];
  // f32-exact cosine (for the margin term)
  const float4* ip = (const float4*)(images + (size_t)row * D_DIM);
  const float4* wp = (const float4*)(weight + (size_t)lab * D_DIM);
  float4 a = ip[lane],       b = wp[lane];
  float4 a2 = ip[lane + 64], b2 = wp[lane + 64];
  float dot = a.x*b.x + a.y*b.y + a.z*b.z + a.w*b.w
            + a2.x*b2.x + a2.y*b2.y + a2.z*b2.z + a2.w*b2.w;
  // quantized dot (to cancel the GEMM's target term exactly)
  uint2 ua = ((const uint2*)(ne_q + (size_t)row * D_DIM))[lane];
  uint2 ub = ((const uint2*)(nw_q + (size_t)lab * D_DIM))[lane];
  int id = dp8(ua.x, ub.x) + dp8(ua.y, ub.y);
  #pragma unroll
  for (int off = 1; off < 64; off <<= 1) {
    dot += __shfl_xor(dot, off);
    id  += __shfl_xor(id, off);
  }
  if (lane == 0) {
    // quantized target logit — identical expression to GEMM epilogue
    float ss = sa_img[row] * sb_w[lab];
    float vq = (float)id * ss;
    vq = fminf(fmaxf(vq, -1.f), 1.f);
    float eq = __builtin_amdgcn_exp2f(vq * SCALE_LN2);
    // f32-exact target cosine + ArcFace margin
    float t = dot * img_inv[row] * w_inv[lab];
    t = fminf(fmaxf(t, -1.f), 1.f);
    float tadj = t * COS_M - sqrtf(fmaxf(1.f - t * t, 0.f)) * SIN_M;
    float s = row_sums[row] - eq
            + __builtin_amdgcn_exp2f(tadj * SCALE_LN2);
    loss_buf[row] = logf(s) - 64.f * tadj;
  }
}

// ------------------------------------------------------------ final mean
__global__ void final_reduce(const float* __restrict__ loss_buf,
                             float* __restrict__ out)
{
  __shared__ float sh[16];
  int tid = threadIdx.x;
  float v = loss_buf[tid];
  #pragma unroll
  for (int off = 1; off < 64; off <<= 1) v += __shfl_xor(v, off);
  if ((tid & 63) == 0) sh[tid >> 6] = v;
  __syncthreads();
  if (tid < 16) {
    float w = sh[tid];
    #pragma unroll
    for (int off = 1; off < 16; off <<= 1) w += __shfl_xor(w, off);
    if (tid == 0) out[0] = w * (1.0f / 1024.0f);
  }
}

// ----------------------------------------------------------------- launch
extern "C" void kernel_launch(void* const* d_in, const int* in_sizes, int n_in,
                              void* d_out, int out_size, void* d_ws, size_t ws_size,
                              hipStream_t stream) {
  const float* images = (const float*)d_in[0];
  const int*   labels = (const int*)d_in[1];
  const float* weight = (const float*)d_in[2];
  float* out = (float*)d_out;
  char* ws = (char*)d_ws;

  // workspace layout (512B-aligned offsets)
  float*       row_sums = (float*)(ws + 0);          //  4 KB
  float*       loss_buf = (float*)(ws + 4096);       //  4 KB
  float*       img_inv  = (float*)(ws + 8192);       //  4 KB
  float*       w_inv    = (float*)(ws + 12288);      //  ~400 KB
  float*       sa_img   = (float*)(ws + 413696);     //  4 KB
  float*       sb_w     = (float*)(ws + 417792);     //  ~400 KB (C_PAD)
  float*       partials = (float*)(ws + 819200);     //  ~1.6 MB [391][1024]
  signed char* ne_q     = (signed char*)(ws + 2420736);  // 512 KB [1024][512]
  signed char* nw_q     = (signed char*)(ws + 2945024);  // ~51 MB [C_PAD][512]

  norm_q<<<N_IMG / 4, 256, 0, stream>>>(images, ne_q, sa_img, img_inv,
                                        N_IMG, N_IMG);
  norm_q<<<C_PAD / 4, 256, 0, stream>>>(weight, nw_q, sb_w, w_inv,
                                        C_CLS, C_PAD);
  gemm_fused<<<NWG, 512, 0, stream>>>(ne_q, nw_q, sa_img, sb_w, partials);
  reduce_partials<<<4, 256, 0, stream>>>(partials, row_sums);
  fix_loss<<<N_IMG / 4, 256, 0, stream>>>(images, weight, labels, img_inv,
                                          w_inv, ne_q, nw_q, sa_img, sb_w,
                                          row_sums, loss_buf);
  final_reduce<<<1, 1024, 0, stream>>>(loss_buf, out);
}

// Round 7
// 177.875 us; speedup vs baseline: 1.5841x; 1.0212x over previous
//
#include <hip/hip_runtime.h>
#include <cstdint>

#define N_IMG 1024
#define D_DIM 512
#define C_CLS 100000
#define C_PAD 100096            // 391 * 256
#define NT_N 391
#define NWG (4 * NT_N)          // 1564 blocks
#define SCALE_LN2 92.33248261689366f  // 64 / ln(2)
#define COS_M 0.8775825618903728f
#define SIN_M 0.479425538604203f

typedef __attribute__((ext_vector_type(4))) int int4v;

#define GLD16(g, l) __builtin_amdgcn_global_load_lds( \
    (const __attribute__((address_space(1))) void*)(g), \
    (__attribute__((address_space(3))) void*)(l), 16, 0, 0)

static __device__ __forceinline__ uint pk4(float a, float b, float c, float d,
                                           float qs) {
  int ia = (int)rintf(a * qs), ib = (int)rintf(b * qs);
  int ic = (int)rintf(c * qs), id = (int)rintf(d * qs);
  return (ia & 255) | ((ib & 255) << 8) | ((ic & 255) << 16) | ((id & 255) << 24);
}

static __device__ __forceinline__ int dp8(uint a, uint b) {
  int s = 0;
  #pragma unroll
  for (int i = 0; i < 4; ++i)
    s += (int)(signed char)((a >> (8 * i)) & 255) *
         (int)(signed char)((b >> (8 * i)) & 255);
  return s;
}

// --------------------------- row L2-normalize + symmetric int8 quantization
__global__ __launch_bounds__(256) void norm_q(
    const float* __restrict__ src, signed char* __restrict__ dst,
    float* __restrict__ scale, float* __restrict__ inv, int nvalid, int nrows)
{
  int row = blockIdx.x * 4 + (threadIdx.x >> 6);
  int lane = threadIdx.x & 63;
  if (row >= nrows) return;
  if (row >= nvalid) {                 // pad rows: zero q + zero scale
    uint2 z; z.x = 0u; z.y = 0u;
    ((uint2*)(dst + (size_t)row * D_DIM))[lane] = z;
    if (lane == 0) scale[row] = 0.f;
    return;
  }
  const float4* sp = (const float4*)(src + (size_t)row * D_DIM);
  float4 a = sp[2 * lane], b = sp[2 * lane + 1];   // 8 consecutive elements
  float ss = a.x*a.x + a.y*a.y + a.z*a.z + a.w*a.w
           + b.x*b.x + b.y*b.y + b.z*b.z + b.w*b.w;
  float am = fmaxf(fmaxf(fmaxf(fabsf(a.x), fabsf(a.y)),
                         fmaxf(fabsf(a.z), fabsf(a.w))),
                   fmaxf(fmaxf(fabsf(b.x), fabsf(b.y)),
                         fmaxf(fabsf(b.z), fabsf(b.w))));
  #pragma unroll
  for (int off = 1; off < 64; off <<= 1) {
    ss += __shfl_xor(ss, off);
    am = fmaxf(am, __shfl_xor(am, off));
  }
  am = fmaxf(am, 1e-30f);
  float iv = 1.0f / fmaxf(sqrtf(ss), 1e-12f);
  float qs = 127.0f / am;
  if (lane == 0) { inv[row] = iv; scale[row] = am * iv * (1.0f / 127.0f); }
  uint2 o;
  o.x = pk4(a.x, a.y, a.z, a.w, qs);
  o.y = pk4(b.x, b.y, b.z, b.w, qs);
  ((uint2*)(dst + (size_t)row * D_DIM))[lane] = o;
}

// ------------------------------------- fused i8 GEMM + exp + row-reduce
// 256x256 tile, BK=64, 8 waves (2Mx4N), mfma_i32_16x16x64_i8.
// 2-slot LDS double-buffer (66 KB -> 2 blocks/CU resident: cross-block TLP
// is the latency-hiding mechanism). One s_barrier + one own-wave vmcnt(0)
// per K-tile, 32 MFMA per barrier, setprio around the MFMA cluster.
// LDS XOR swizzle on 16B granules with ((row>>1)&3)  -> 2 lanes/bank-window
// per quarter-wave phase = conflict-free (round-6's (row&3) was 4-way).
__global__ __launch_bounds__(512, 2) void gemm_fused(
    const signed char* __restrict__ A, const signed char* __restrict__ B,
    const float* __restrict__ sa_img, const float* __restrict__ sb_w,
    float* __restrict__ partials)
{
  __shared__ __align__(16) signed char Aq[2][256 * 64];
  __shared__ __align__(16) signed char Bq[2][256 * 64];
  __shared__ float red[256];

  const int tid  = threadIdx.x;
  const int lane = tid & 63;
  const int w    = tid >> 6;
  const int l15  = lane & 15;
  const int l4   = lane >> 4;

  // T1 bijective swizzle: NWG=1564, q=195, r=4
  const int p   = blockIdx.x;
  const int xcd = p & 7, idx = p >> 3;
  const int g   = (xcd < 4 ? xcd * 196 : 784 + (xcd - 4) * 195) + idx;
  const int bm  = g & 3;
  const int bn  = g >> 2;
  const int wr  = w >> 2, wc = w & 3;   // 2x4 wave grid

  int4v acc[8][4] = {};
  if (tid < 256) red[tid] = 0.f;

  // staging: lane l -> local row l>>3... (row_local = l>>2, 16B slot = l&3);
  // source chunk pre-swizzled by (row>>1)&3 = (l>>3)&3
  const int sgcol = ((lane & 3) ^ ((lane >> 3) & 3)) << 4;
  const int grow  = (w << 4) + (lane >> 2);
  const size_t a_base = (size_t)(bm * 256) * D_DIM;
  const size_t b_base = (size_t)(bn * 256) * D_DIM;
  // read-side swizzle: slot = l4 ^ ((row>>1)&3), row = 16k + l15
  const int sw4 = ((l4 ^ ((l15 >> 1) & 3)) << 4);

  #define STG_A(slot, kt, half) GLD16( \
      A + a_base + (size_t)((half)*128 + grow) * D_DIM + (kt)*64 + sgcol, \
      &Aq[slot][((half)*128 + (w << 4)) * 64])
  #define STG_B(slot, kt, half) GLD16( \
      B + b_base + (size_t)((half)*128 + grow) * D_DIM + (kt)*64 + sgcol, \
      &Bq[slot][((half)*128 + (w << 4)) * 64])
  #define STAGE(slot, kt) do { \
    STG_A(slot, kt, 0); STG_B(slot, kt, 0); \
    STG_A(slot, kt, 1); STG_B(slot, kt, 1); } while (0)

  #define READ_B() do { _Pragma("unroll") \
    for (int n = 0; n < 4; ++n) { \
      int byt = (wc*64 + n*16 + l15) * 64 + sw4; \
      bf[n] = *(const int4v*)(Bb + byt); } } while (0)
  #define READ_A(dst, mh) do { _Pragma("unroll") \
    for (int mi = 0; mi < 4; ++mi) { \
      int byt = (wr*128 + (mh)*64 + mi*16 + l15) * 64 + sw4; \
      dst[mi] = *(const int4v*)(Ab + byt); } } while (0)
  #define MFMA16(mh, af) do { _Pragma("unroll") \
    for (int mi = 0; mi < 4; ++mi) { _Pragma("unroll") \
      for (int n = 0; n < 4; ++n) \
        acc[(mh)*4+mi][n] = __builtin_amdgcn_mfma_i32_16x16x64_i8( \
            af[mi], bf[n], acc[(mh)*4+mi][n], 0, 0, 0); } } while (0)

  #define BAR()   do { asm volatile("" ::: "memory"); \
                       __builtin_amdgcn_s_barrier(); \
                       asm volatile("" ::: "memory"); } while (0)
  #define VM0()   asm volatile("s_waitcnt vmcnt(0)" ::: "memory")

  // prologue: stage tile 0, drain, barrier
  STAGE(0, 0);
  VM0();
  BAR();

  #pragma unroll
  for (int kt = 0; kt < 8; ++kt) {
    const int cur = kt & 1;
    const char* Ab = (const char*)Aq[cur];
    const char* Bb = (const char*)Bq[cur];

    if (kt < 7) STAGE(cur ^ 1, kt + 1);   // issue first (oldest in queue)

    int4v af0[4], af1[4], bf[4];
    READ_B(); READ_A(af0, 0); READ_A(af1, 1);   // 12 x ds_read_b128
    __builtin_amdgcn_s_setprio(1);
    MFMA16(0, af0);
    MFMA16(1, af1);
    __builtin_amdgcn_s_setprio(0);

    if (kt < 7) VM0();   // own 4 stage loads: issued a whole body ago (L2)
    BAR();
  }

  // epilogue: dequant, clip, exp(64x), reduce 256 block-cols per row
  // C/D layout (m89, dtype-independent): col = lane&15, row = (lane>>4)*4 + j
  const int rowg0 = bm * 256 + wr * 128;
  float sbv[4];
  #pragma unroll
  for (int n = 0; n < 4; ++n)
    sbv[n] = sb_w[bn * 256 + wc * 64 + n * 16 + l15];
  #pragma unroll
  for (int m = 0; m < 8; ++m) {
    #pragma unroll
    for (int j = 0; j < 4; ++j) {
      float sa = sa_img[rowg0 + m * 16 + l4 * 4 + j];
      float s = 0.f;
      #pragma unroll
      for (int n = 0; n < 4; ++n) {
        int gcol = bn * 256 + wc * 64 + n * 16 + l15;
        float ss = sa * sbv[n];
        float v = (float)acc[m][n][j] * ss;
        v = fminf(fmaxf(v, -1.f), 1.f);
        float e = __builtin_amdgcn_exp2f(v * SCALE_LN2);
        s += (gcol < C_CLS) ? e : 0.f;
      }
      #pragma unroll
      for (int off = 1; off < 16; off <<= 1) s += __shfl_xor(s, off);
      if (l15 == 0)
        atomicAdd(&red[wr * 128 + m * 16 + l4 * 4 + j], s);  // LDS
    }
  }
  __syncthreads();
  if (tid < 256)
    partials[(size_t)bn * 1024 + bm * 256 + tid] = red[tid];

  #undef STG_A
  #undef STG_B
  #undef STAGE
  #undef READ_A
  #undef READ_B
  #undef MFMA16
  #undef BAR
  #undef VM0
}

// ---------------------------------------------------------------- zero rows
__global__ void zero_rows(float* p) {
  p[blockIdx.x * 256 + threadIdx.x] = 0.f;
}

// ------------------- row_sums[r] += partials chunk sums (32 blocks, atomic)
__global__ __launch_bounds__(256) void reduce_partials(
    const float* __restrict__ partials, float* __restrict__ row_sums)
{
  const int c = blockIdx.x >> 2;                  // bn-chunk 0..7
  const int gid = (blockIdx.x & 3) * 256 + threadIdx.x;
  const int b0 = c * 49;
  const int b1 = (b0 + 49 < NT_N) ? b0 + 49 : NT_N;
  float s = 0.f;
  for (int bn = b0; bn < b1; ++bn)
    s += partials[(size_t)bn * 1024 + gid];
  atomicAdd(&row_sums[gid], s);
}

// ---------------------------------------- per-row margin fixup + row loss
__global__ __launch_bounds__(256) void fix_loss(
    const float* __restrict__ images, const float* __restrict__ weight,
    const int* __restrict__ labels, const float* __restrict__ img_inv,
    const float* __restrict__ w_inv,
    const signed char* __restrict__ ne_q, const signed char* __restrict__ nw_q,
    const float* __restrict__ sa_img, const float* __restrict__ sb_w,
    const float* __restrict__ row_sums, float* __restrict__ loss_buf)
{
  int row = blockIdx.x * 4 + (threadIdx.x >> 6);
  int lane = threadIdx.x & 63;
  int lab = labels[row];
  const float4* ip = (const float4*)(images + (size_t)row * D_DIM);
  const float4* wp = (const float4*)(weight + (size_t)lab * D_DIM);
  float4 a = ip[lane],       b = wp[lane];
  float4 a2 = ip[lane + 64], b2 = wp[lane + 64];
  float dot = a.x*b.x + a.y*b.y + a.z*b.z + a.w*b.w
            + a2.x*b2.x + a2.y*b2.y + a2.z*b2.z + a2.w*b2.w;
  uint2 ua = ((const uint2*)(ne_q + (size_t)row * D_DIM))[lane];
  uint2 ub = ((const uint2*)(nw_q + (size_t)lab * D_DIM))[lane];
  int id = dp8(ua.x, ub.x) + dp8(ua.y, ub.y);
  #pragma unroll
  for (int off = 1; off < 64; off <<= 1) {
    dot += __shfl_xor(dot, off);
    id  += __shfl_xor(id, off);
  }
  if (lane == 0) {
    // quantized target logit — identical expression to GEMM epilogue
    float ss = sa_img[row] * sb_w[lab];
    float vq = (float)id * ss;
    vq = fminf(fmaxf(vq, -1.f), 1.f);
    float eq = __builtin_amdgcn_exp2f(vq * SCALE_LN2);
    // f32-exact target cosine + ArcFace margin
    float t = dot * img_inv[row] * w_inv[lab];
    t = fminf(fmaxf(t, -1.f), 1.f);
    float tadj = t * COS_M - sqrtf(fmaxf(1.f - t * t, 0.f)) * SIN_M;
    float s = row_sums[row] - eq
            + __builtin_amdgcn_exp2f(tadj * SCALE_LN2);
    loss_buf[row] = logf(s) - 64.f * tadj;
  }
}

// ------------------------------------------------------------ final mean
__global__ void final_reduce(const float* __restrict__ loss_buf,
                             float* __restrict__ out)
{
  __shared__ float sh[16];
  int tid = threadIdx.x;
  float v = loss_buf[tid];
  #pragma unroll
  for (int off = 1; off < 64; off <<= 1) v += __shfl_xor(v, off);
  if ((tid & 63) == 0) sh[tid >> 6] = v;
  __syncthreads();
  if (tid < 16) {
    float w = sh[tid];
    #pragma unroll
    for (int off = 1; off < 16; off <<= 1) w += __shfl_xor(w, off);
    if (tid == 0) out[0] = w * (1.0f / 1024.0f);
  }
}

// ----------------------------------------------------------------- launch
extern "C" void kernel_launch(void* const* d_in, const int* in_sizes, int n_in,
                              void* d_out, int out_size, void* d_ws, size_t ws_size,
                              hipStream_t stream) {
  const float* images = (const float*)d_in[0];
  const int*   labels = (const int*)d_in[1];
  const float* weight = (const float*)d_in[2];
  float* out = (float*)d_out;
  char* ws = (char*)d_ws;

  // workspace layout (512B-aligned offsets)
  float*       row_sums = (float*)(ws + 0);          //  4 KB
  float*       loss_buf = (float*)(ws + 4096);       //  4 KB
  float*       img_inv  = (float*)(ws + 8192);       //  4 KB
  float*       w_inv    = (float*)(ws + 12288);      //  ~400 KB
  float*       sa_img   = (float*)(ws + 413696);     //  4 KB
  float*       sb_w     = (float*)(ws + 417792);     //  ~400 KB (C_PAD)
  float*       partials = (float*)(ws + 819200);     //  ~1.6 MB [391][1024]
  signed char* ne_q     = (signed char*)(ws + 2420736);  // 512 KB [1024][512]
  signed char* nw_q     = (signed char*)(ws + 2945024);  // ~51 MB [C_PAD][512]

  norm_q<<<N_IMG / 4, 256, 0, stream>>>(images, ne_q, sa_img, img_inv,
                                        N_IMG, N_IMG);
  norm_q<<<C_PAD / 4, 256, 0, stream>>>(weight, nw_q, sb_w, w_inv,
                                        C_CLS, C_PAD);
  zero_rows<<<4, 256, 0, stream>>>(row_sums);
  gemm_fused<<<NWG, 512, 0, stream>>>(ne_q, nw_q, sa_img, sb_w, partials);
  reduce_partials<<<32, 256, 0, stream>>>(partials, row_sums);
  fix_loss<<<N_IMG / 4, 256, 0, stream>>>(images, weight, labels, img_inv,
                                          w_inv, ne_q, nw_q, sa_img, sb_w,
                                          row_sums, loss_buf);
  final_reduce<<<1, 1024, 0, stream>>>(loss_buf, out);
}